// Round 1
// baseline (539.953 us; speedup 1.0000x reference)
//
#include <hip/hip_runtime.h>
#include <math.h>

// ---------------------------------------------------------------------------
// 3-layer GCN (PyG GCNConv semantics): per layer
//   h = x @ W ; out[dst] += dinv[src]*dinv[dst] * h[src] (+ self loop) ; + b
// deg/dinv and CSR are edge-structure-only -> built once, reused by 3 layers.
// ---------------------------------------------------------------------------

#define NFEAT_IN 128

__global__ void count_kernel(const int* __restrict__ dst, int* __restrict__ cnt, int E) {
    int i = blockIdx.x * blockDim.x + threadIdx.x;
    if (i < E) atomicAdd(&cnt[dst[i]], 1);
}

// Single-block exclusive scan over cnt -> offs[0..n], also dinv[v]=rsqrt(cnt[v]+1)
__global__ __launch_bounds__(1024) void scan_kernel(const int* __restrict__ cnt,
                                                    int* __restrict__ offs,
                                                    float* __restrict__ dinv, int n) {
    __shared__ int wsum[16];
    __shared__ int carry_s;
    int tid = threadIdx.x;
    int lane = tid & 63;
    int wid = tid >> 6;
    if (tid == 0) carry_s = 0;
    __syncthreads();
    for (int base = 0; base < n; base += 1024) {
        int i = base + tid;
        int v = (i < n) ? cnt[i] : 0;
        if (i < n) dinv[i] = rsqrtf((float)(v + 1));  // +1 self-loop; always > 0
        // inclusive scan within wave (64 lanes)
        int s = v;
        #pragma unroll
        for (int off = 1; off < 64; off <<= 1) {
            int t = __shfl_up(s, off, 64);
            if (lane >= off) s += t;
        }
        if (lane == 63) wsum[wid] = s;
        __syncthreads();
        int wbase = 0;
        for (int w = 0; w < wid; ++w) wbase += wsum[w];
        int carry = carry_s;
        __syncthreads();  // everyone has read carry_s and wsum
        if (i < n) offs[i] = carry + wbase + (s - v);
        if (tid == 1023) carry_s = carry + wbase + s;
        __syncthreads();
    }
    if (tid == 0) offs[n] = carry_s;
}

__global__ void fill_kernel(const int* __restrict__ src, const int* __restrict__ dst,
                            const int* __restrict__ offs, int* __restrict__ cur,
                            const float* __restrict__ dinv,
                            int* __restrict__ srcs, float* __restrict__ wsrc, int E) {
    int i = blockIdx.x * blockDim.x + threadIdx.x;
    if (i >= E) return;
    int d = dst[i];
    int s = src[i];
    int p = offs[d] + atomicAdd(&cur[d], 1);
    srcs[p] = s;
    wsrc[p] = dinv[s];
}

// fp32 GEMM  Y[nrows,MOUT] = X[nrows,128] @ W[128,MOUT]
// 256 threads, tile 32 rows; thread (ty,tx): 2 rows x (MOUT/16) cols
template <int MOUT>
__global__ __launch_bounds__(256) void gemm_kernel(const float* __restrict__ X,
                                                   const float* __restrict__ W,
                                                   float* __restrict__ Y, int nrows) {
    constexpr int K = 128;
    constexpr int TR = 32;
    constexpr int CJ = MOUT / 16;
    __shared__ float Ws[K * MOUT];
    __shared__ float Xs[TR * K];
    int tid = threadIdx.x;
    for (int i = tid * 4; i < K * MOUT; i += 256 * 4) {
        *(float4*)&Ws[i] = *(const float4*)&W[i];
    }
    int blockRow = blockIdx.x * TR;
    for (int i = tid * 4; i < TR * K; i += 256 * 4) {
        int r = blockRow + i / K;
        float4 v;
        if (r < nrows) v = *(const float4*)&X[r * K + (i % K)];
        else { v.x = v.y = v.z = v.w = 0.f; }
        *(float4*)&Xs[i] = v;
    }
    __syncthreads();
    int tx = tid % 16, ty = tid / 16;
    float acc[2][CJ];
    #pragma unroll
    for (int r = 0; r < 2; ++r)
        #pragma unroll
        for (int j = 0; j < CJ; ++j) acc[r][j] = 0.f;
    int c0 = tx * CJ;
    const float* xr0 = &Xs[(ty * 2) * K];
    const float* xr1 = &Xs[(ty * 2 + 1) * K];
    #pragma unroll 4
    for (int k = 0; k < K; ++k) {
        float a0 = xr0[k];
        float a1 = xr1[k];
        #pragma unroll
        for (int j4 = 0; j4 < CJ; j4 += 4) {
            float4 w = *(float4*)&Ws[k * MOUT + c0 + j4];
            acc[0][j4 + 0] += a0 * w.x; acc[0][j4 + 1] += a0 * w.y;
            acc[0][j4 + 2] += a0 * w.z; acc[0][j4 + 3] += a0 * w.w;
            acc[1][j4 + 0] += a1 * w.x; acc[1][j4 + 1] += a1 * w.y;
            acc[1][j4 + 2] += a1 * w.z; acc[1][j4 + 3] += a1 * w.w;
        }
    }
    int r0 = blockRow + ty * 2;
    #pragma unroll
    for (int r = 0; r < 2; ++r) {
        if (r0 + r < nrows) {
            #pragma unroll
            for (int j4 = 0; j4 < CJ; j4 += 4) {
                float4 v;
                v.x = acc[r][j4 + 0]; v.y = acc[r][j4 + 1];
                v.z = acc[r][j4 + 2]; v.w = acc[r][j4 + 3];
                *(float4*)&Y[(size_t)(r0 + r) * MOUT + c0 + j4] = v;
            }
        }
    }
}

// CSR aggregation: one wave per node. out[v] = dinv[v]*(dinv[v]*h[v] + sum_e dinv[s]*h[s]) + b
template <int NF, bool ELU>
__global__ __launch_bounds__(256) void agg_kernel(const float* __restrict__ H,
                                                  const int* __restrict__ offs,
                                                  const int* __restrict__ srcs,
                                                  const float* __restrict__ wsrc,
                                                  const float* __restrict__ dinv,
                                                  const float* __restrict__ bias,
                                                  float* __restrict__ out, int n) {
    int lane = threadIdx.x & 63;
    int v = blockIdx.x * 4 + (threadIdx.x >> 6);
    if (v >= n) return;
    float dv = dinv[v];
    int e0 = offs[v], e1 = offs[v + 1];
    if (NF == 128) {
        float acc0 = dv * H[(size_t)v * 128 + lane];
        float acc1 = dv * H[(size_t)v * 128 + 64 + lane];
        for (int e = e0; e < e1; ++e) {
            int s = srcs[e];
            float w = wsrc[e];
            acc0 += w * H[(size_t)s * 128 + lane];
            acc1 += w * H[(size_t)s * 128 + 64 + lane];
        }
        float r0 = dv * acc0 + bias[lane];
        float r1 = dv * acc1 + bias[64 + lane];
        if (ELU) {
            r0 = r0 > 0.f ? r0 : (expf(r0) - 1.f);
            r1 = r1 > 0.f ? r1 : (expf(r1) - 1.f);
        }
        out[(size_t)v * 128 + lane] = r0;
        out[(size_t)v * 128 + 64 + lane] = r1;
    } else {
        float acc = dv * H[(size_t)v * NF + lane];
        for (int e = e0; e < e1; ++e) {
            acc += wsrc[e] * H[(size_t)srcs[e] * NF + lane];
        }
        float r = dv * acc + bias[lane];
        if (ELU) r = r > 0.f ? r : (expf(r) - 1.f);
        out[(size_t)v * NF + lane] = r;
    }
}

static inline size_t alignup(size_t x) { return (x + 255) & ~(size_t)255; }

extern "C" void kernel_launch(void* const* d_in, const int* in_sizes, int n_in,
                              void* d_out, int out_size, void* d_ws, size_t ws_size,
                              hipStream_t stream) {
    const float* x  = (const float*)d_in[0];
    const int*   ei = (const int*)d_in[1];
    const float* W1 = (const float*)d_in[2];
    const float* b1 = (const float*)d_in[3];
    const float* W2 = (const float*)d_in[4];
    const float* b2 = (const float*)d_in[5];
    const float* W3 = (const float*)d_in[6];
    const float* b3 = (const float*)d_in[7];
    float* out = (float*)d_out;

    const int N = in_sizes[0] / NFEAT_IN;  // 50000
    const int E = in_sizes[1] / 2;         // 800000
    const int* src = ei;
    const int* dst = ei + E;

    // workspace carve
    char* w = (char*)d_ws;
    int* cnt = (int*)w;                 // [N]  (cnt and cur adjacent -> single memset)
    int* cur = cnt + N;                 // [N]
    w += alignup((size_t)2 * N * sizeof(int));
    int* offs = (int*)w;  w += alignup((size_t)(N + 1) * sizeof(int));
    float* dinv = (float*)w; w += alignup((size_t)N * sizeof(float));
    int* srcs = (int*)w;  w += alignup((size_t)E * sizeof(int));
    float* wsrc = (float*)w; w += alignup((size_t)E * sizeof(float));
    float* hA = (float*)w; w += alignup((size_t)N * 128 * sizeof(float));
    float* hB = (float*)w; w += alignup((size_t)N * 128 * sizeof(float));

    // --- build CSR + dinv (shared by all 3 layers) ---
    hipMemsetAsync(cnt, 0, (size_t)2 * N * sizeof(int), stream);
    count_kernel<<<(E + 255) / 256, 256, 0, stream>>>(dst, cnt, E);
    scan_kernel<<<1, 1024, 0, stream>>>(cnt, offs, dinv, N);
    fill_kernel<<<(E + 255) / 256, 256, 0, stream>>>(src, dst, offs, cur, dinv, srcs, wsrc, E);

    int gemm_grid = (N + 31) / 32;
    int agg_grid = (N + 3) / 4;

    // layer 1: h = x@W1 ; agg+bias+ELU
    gemm_kernel<128><<<gemm_grid, 256, 0, stream>>>(x, W1, hA, N);
    agg_kernel<128, true><<<agg_grid, 256, 0, stream>>>(hA, offs, srcs, wsrc, dinv, b1, hB, N);
    // layer 2
    gemm_kernel<128><<<gemm_grid, 256, 0, stream>>>(hB, W2, hA, N);
    agg_kernel<128, true><<<agg_grid, 256, 0, stream>>>(hA, offs, srcs, wsrc, dinv, b2, hB, N);
    // layer 3 (128 -> 64), no ELU
    gemm_kernel<64><<<gemm_grid, 256, 0, stream>>>(hB, W3, hA, N);
    agg_kernel<64, false><<<agg_grid, 256, 0, stream>>>(hA, offs, srcs, wsrc, dinv, b3, out, N);
}

// Round 2
// 358.148 us; speedup vs baseline: 1.5076x; 1.5076x over previous
//
#include <hip/hip_runtime.h>
#include <math.h>

// ---------------------------------------------------------------------------
// 3-layer GCN (PyG GCNConv semantics): per layer
//   h = x @ W ; out[v] = dinv[v]*(dinv[v]*h[v] + sum_e dinv[s]*h[s]) + b
// CSR + dinv built once (edge structure shared by all 3 layers).
// ---------------------------------------------------------------------------

#define NFEAT_IN 128
#define SCAN_CHUNK 2048

__global__ void count_kernel(const int* __restrict__ dst, int* __restrict__ cnt, int E) {
    int i = blockIdx.x * blockDim.x + threadIdx.x;
    if (i < E) atomicAdd(&cnt[dst[i]], 1);
}

// pass 1: per-block (2048-elem chunk) reduction -> bsum[b]
__global__ __launch_bounds__(256) void reduce_kernel(const int* __restrict__ cnt,
                                                     int* __restrict__ bsum, int n) {
    __shared__ int wtot[4];
    int b = blockIdx.x, t = threadIdx.x;
    int base = b * SCAN_CHUNK + t * 8;
    int s = 0;
    if (base + 8 <= n) {
        int4 a = *(const int4*)&cnt[base];
        int4 c = *(const int4*)&cnt[base + 4];
        s = a.x + a.y + a.z + a.w + c.x + c.y + c.z + c.w;
    } else {
        for (int i = 0; i < 8; ++i) if (base + i < n) s += cnt[base + i];
    }
    int lane = t & 63, wid = t >> 6;
    #pragma unroll
    for (int off = 32; off > 0; off >>= 1) s += __shfl_down(s, off, 64);
    if (lane == 0) wtot[wid] = s;
    __syncthreads();
    if (t == 0) bsum[b] = wtot[0] + wtot[1] + wtot[2] + wtot[3];
}

// pass 2: single-wave scan of block sums (nb <= 64); bsum becomes exclusive base
__global__ void scanb_kernel(int* __restrict__ bsum, int nb, int* __restrict__ offs, int n) {
    int lane = threadIdx.x;
    int v = (lane < nb) ? bsum[lane] : 0;
    int inc = v;
    #pragma unroll
    for (int off = 1; off < 64; off <<= 1) {
        int t = __shfl_up(inc, off, 64);
        if (lane >= off) inc += t;
    }
    if (lane < nb) bsum[lane] = inc - v;  // exclusive
    if (lane == 63) offs[n] = inc;        // total
}

// pass 3: local scan within chunk; write offs, pos (=offs copy), dinv
__global__ __launch_bounds__(256) void scan3_kernel(const int* __restrict__ cnt,
                                                    const int* __restrict__ bbase,
                                                    int* __restrict__ offs,
                                                    int* __restrict__ pos,
                                                    float* __restrict__ dinv, int n) {
    __shared__ int wtot[4];
    int b = blockIdx.x, t = threadIdx.x;
    int base = b * SCAN_CHUNK + t * 8;
    int v[8];
    #pragma unroll
    for (int i = 0; i < 8; ++i) v[i] = (base + i < n) ? cnt[base + i] : 0;
    int psum[8], s = 0;
    #pragma unroll
    for (int i = 0; i < 8; ++i) { psum[i] = s; s += v[i]; }
    int lane = t & 63, wid = t >> 6;
    int inc = s;
    #pragma unroll
    for (int off = 1; off < 64; off <<= 1) {
        int tt = __shfl_up(inc, off, 64);
        if (lane >= off) inc += tt;
    }
    if (lane == 63) wtot[wid] = inc;
    __syncthreads();
    int wb = 0;
    for (int w = 0; w < wid; ++w) wb += wtot[w];
    int tbase = bbase[b] + wb + (inc - s);
    #pragma unroll
    for (int i = 0; i < 8; ++i) {
        if (base + i < n) {
            int o = tbase + psum[i];
            offs[base + i] = o;
            pos[base + i] = o;
            dinv[base + i] = rsqrtf((float)(v[i] + 1));  // +1 self-loop
        }
    }
}

__global__ void fill_kernel(const int* __restrict__ src, const int* __restrict__ dst,
                            int* __restrict__ pos, const float* __restrict__ dinv,
                            int* __restrict__ srcs, float* __restrict__ wsrc, int E) {
    int i = blockIdx.x * blockDim.x + threadIdx.x;
    if (i >= E) return;
    int d = dst[i];
    int s = src[i];
    int p = atomicAdd(&pos[d], 1);
    srcs[p] = s;
    wsrc[p] = dinv[s];
}

// fp32 GEMM  Y[nrows,BN] = X[nrows,128] @ W[128,BN];  BM=64, BK=32
// Xs stored transposed [BK][BM] -> conflict-free ds_read_b128 of 4 rows.
// thread (tx,ty): rows ty*4..+3, cols tx+16*j -> conflict-free Ws reads.
template <int BN>
__global__ __launch_bounds__(256) void gemm_kernel(const float* __restrict__ X,
                                                   const float* __restrict__ W,
                                                   float* __restrict__ Y, int nrows) {
    constexpr int K = 128, BM = 64, BK = 32;
    constexpr int JJ = BN / 16;
    __shared__ float Xs[BK][BM];
    __shared__ float Ws[BK * BN];
    int t = threadIdx.x;
    int tx = t & 15, ty = t >> 4;
    int blockRow = blockIdx.x * BM;
    float acc[4][JJ];
    #pragma unroll
    for (int r = 0; r < 4; ++r)
        #pragma unroll
        for (int j = 0; j < JJ; ++j) acc[r][j] = 0.f;

    for (int kt = 0; kt < K; kt += BK) {
        // stage X tile (transposed): thread t covers row=t/4, cols (t%4)*8..+7
        {
            int row = t >> 2;
            int c = (t & 3) * 8;
            int gr = blockRow + row;
            float4 a, d4;
            if (gr < nrows) {
                a  = *(const float4*)&X[(size_t)gr * K + kt + c];
                d4 = *(const float4*)&X[(size_t)gr * K + kt + c + 4];
            } else {
                a.x=a.y=a.z=a.w=0.f; d4=a;
            }
            Xs[c + 0][row] = a.x;  Xs[c + 1][row] = a.y;
            Xs[c + 2][row] = a.z;  Xs[c + 3][row] = a.w;
            Xs[c + 4][row] = d4.x; Xs[c + 5][row] = d4.y;
            Xs[c + 6][row] = d4.z; Xs[c + 7][row] = d4.w;
        }
        // stage W tile (flat contiguous rows kt..kt+BK of W[128][BN])
        for (int i = t * 4; i < BK * BN; i += 256 * 4)
            *(float4*)&Ws[i] = *(const float4*)&W[(size_t)kt * BN + i];
        __syncthreads();
        #pragma unroll 4
        for (int k = 0; k < BK; ++k) {
            float4 xa = *(const float4*)&Xs[k][ty * 4];
            float wv[JJ];
            #pragma unroll
            for (int j = 0; j < JJ; ++j) wv[j] = Ws[k * BN + tx + 16 * j];
            #pragma unroll
            for (int j = 0; j < JJ; ++j) {
                acc[0][j] += xa.x * wv[j];
                acc[1][j] += xa.y * wv[j];
                acc[2][j] += xa.z * wv[j];
                acc[3][j] += xa.w * wv[j];
            }
        }
        __syncthreads();
    }
    #pragma unroll
    for (int r = 0; r < 4; ++r) {
        int gr = blockRow + ty * 4 + r;
        if (gr < nrows) {
            #pragma unroll
            for (int j = 0; j < JJ; ++j)
                Y[(size_t)gr * BN + tx + 16 * j] = acc[r][j];
        }
    }
}

// CSR aggregation, NF=128: one wave per node, float2 per lane, 4x edge unroll.
template <bool ELU>
__global__ __launch_bounds__(256) void agg128_kernel(const float* __restrict__ H,
                                                     const int* __restrict__ offs,
                                                     const int* __restrict__ srcs,
                                                     const float* __restrict__ wsrc,
                                                     const float* __restrict__ dinv,
                                                     const float* __restrict__ bias,
                                                     float* __restrict__ out, int n) {
    int lane = threadIdx.x & 63;
    int v = blockIdx.x * 4 + (threadIdx.x >> 6);
    if (v >= n) return;
    const float2* __restrict__ H2 = (const float2*)H;
    float dv = dinv[v];
    int e0 = offs[v], e1 = offs[v + 1];
    float2 hv = H2[(size_t)v * 64 + lane];
    float ax = dv * hv.x, ay = dv * hv.y;
    int e = e0;
    for (; e + 4 <= e1; e += 4) {
        int s0 = srcs[e], s1 = srcs[e + 1], s2 = srcs[e + 2], s3 = srcs[e + 3];
        float w0 = wsrc[e], w1 = wsrc[e + 1], w2 = wsrc[e + 2], w3 = wsrc[e + 3];
        float2 h0 = H2[(size_t)s0 * 64 + lane];
        float2 h1 = H2[(size_t)s1 * 64 + lane];
        float2 h2 = H2[(size_t)s2 * 64 + lane];
        float2 h3 = H2[(size_t)s3 * 64 + lane];
        ax += w0 * h0.x; ay += w0 * h0.y;
        ax += w1 * h1.x; ay += w1 * h1.y;
        ax += w2 * h2.x; ay += w2 * h2.y;
        ax += w3 * h3.x; ay += w3 * h3.y;
    }
    for (; e < e1; ++e) {
        int s = srcs[e];
        float w = wsrc[e];
        float2 h = H2[(size_t)s * 64 + lane];
        ax += w * h.x; ay += w * h.y;
    }
    float2 bb = ((const float2*)bias)[lane];
    float rx = dv * ax + bb.x;
    float ry = dv * ay + bb.y;
    if (ELU) {
        rx = rx > 0.f ? rx : expm1f(rx);
        ry = ry > 0.f ? ry : expm1f(ry);
    }
    float2 r; r.x = rx; r.y = ry;
    ((float2*)out)[(size_t)v * 64 + lane] = r;
}

// CSR aggregation, NF=64: one wave per node, scalar per lane, 4x edge unroll.
template <bool ELU>
__global__ __launch_bounds__(256) void agg64_kernel(const float* __restrict__ H,
                                                    const int* __restrict__ offs,
                                                    const int* __restrict__ srcs,
                                                    const float* __restrict__ wsrc,
                                                    const float* __restrict__ dinv,
                                                    const float* __restrict__ bias,
                                                    float* __restrict__ out, int n) {
    int lane = threadIdx.x & 63;
    int v = blockIdx.x * 4 + (threadIdx.x >> 6);
    if (v >= n) return;
    float dv = dinv[v];
    int e0 = offs[v], e1 = offs[v + 1];
    float acc = dv * H[(size_t)v * 64 + lane];
    int e = e0;
    for (; e + 4 <= e1; e += 4) {
        int s0 = srcs[e], s1 = srcs[e + 1], s2 = srcs[e + 2], s3 = srcs[e + 3];
        float w0 = wsrc[e], w1 = wsrc[e + 1], w2 = wsrc[e + 2], w3 = wsrc[e + 3];
        float h0 = H[(size_t)s0 * 64 + lane];
        float h1 = H[(size_t)s1 * 64 + lane];
        float h2 = H[(size_t)s2 * 64 + lane];
        float h3 = H[(size_t)s3 * 64 + lane];
        acc += w0 * h0 + w1 * h1 + w2 * h2 + w3 * h3;
    }
    for (; e < e1; ++e) {
        acc += wsrc[e] * H[(size_t)srcs[e] * 64 + lane];
    }
    float r = dv * acc + bias[lane];
    if (ELU) r = r > 0.f ? r : expm1f(r);
    out[(size_t)v * 64 + lane] = r;
}

static inline size_t alignup(size_t x) { return (x + 255) & ~(size_t)255; }

extern "C" void kernel_launch(void* const* d_in, const int* in_sizes, int n_in,
                              void* d_out, int out_size, void* d_ws, size_t ws_size,
                              hipStream_t stream) {
    const float* x  = (const float*)d_in[0];
    const int*   ei = (const int*)d_in[1];
    const float* W1 = (const float*)d_in[2];
    const float* b1 = (const float*)d_in[3];
    const float* W2 = (const float*)d_in[4];
    const float* b2 = (const float*)d_in[5];
    const float* W3 = (const float*)d_in[6];
    const float* b3 = (const float*)d_in[7];
    float* out = (float*)d_out;

    const int N = in_sizes[0] / NFEAT_IN;  // 50000
    const int E = in_sizes[1] / 2;         // 800000
    const int* src = ei;
    const int* dst = ei + E;

    // workspace carve
    char* w = (char*)d_ws;
    int* cnt  = (int*)w;  w += alignup((size_t)N * sizeof(int));
    int* pos  = (int*)w;  w += alignup((size_t)N * sizeof(int));
    int* offs = (int*)w;  w += alignup((size_t)(N + 1) * sizeof(int));
    float* dinv = (float*)w; w += alignup((size_t)N * sizeof(float));
    int* bsum = (int*)w;  w += alignup((size_t)64 * sizeof(int));
    int* srcs = (int*)w;  w += alignup((size_t)E * sizeof(int));
    float* wsrc = (float*)w; w += alignup((size_t)E * sizeof(float));
    float* hA = (float*)w; w += alignup((size_t)N * 128 * sizeof(float));
    float* hB = (float*)w; w += alignup((size_t)N * 128 * sizeof(float));

    const int nb = (N + SCAN_CHUNK - 1) / SCAN_CHUNK;  // 25 (<= 64 required)

    // --- build CSR + dinv (shared by all 3 layers) ---
    hipMemsetAsync(cnt, 0, (size_t)N * sizeof(int), stream);
    count_kernel<<<(E + 255) / 256, 256, 0, stream>>>(dst, cnt, E);
    reduce_kernel<<<nb, 256, 0, stream>>>(cnt, bsum, N);
    scanb_kernel<<<1, 64, 0, stream>>>(bsum, nb, offs, N);
    scan3_kernel<<<nb, 256, 0, stream>>>(cnt, bsum, offs, pos, dinv, N);
    fill_kernel<<<(E + 255) / 256, 256, 0, stream>>>(src, dst, pos, dinv, srcs, wsrc, E);

    int gemm_grid = (N + 63) / 64;
    int agg_grid = (N + 3) / 4;

    // layer 1
    gemm_kernel<128><<<gemm_grid, 256, 0, stream>>>(x, W1, hA, N);
    agg128_kernel<true><<<agg_grid, 256, 0, stream>>>(hA, offs, srcs, wsrc, dinv, b1, hB, N);
    // layer 2
    gemm_kernel<128><<<gemm_grid, 256, 0, stream>>>(hB, W2, hA, N);
    agg128_kernel<true><<<agg_grid, 256, 0, stream>>>(hA, offs, srcs, wsrc, dinv, b2, hB, N);
    // layer 3 (128 -> 64), no ELU
    gemm_kernel<64><<<gemm_grid, 256, 0, stream>>>(hB, W3, hA, N);
    agg64_kernel<false><<<agg_grid, 256, 0, stream>>>(hA, offs, srcs, wsrc, dinv, b3, out, N);
}

// Round 3
// 354.274 us; speedup vs baseline: 1.5241x; 1.0109x over previous
//
#include <hip/hip_runtime.h>
#include <math.h>

// ---------------------------------------------------------------------------
// 3-layer GCN (PyG GCNConv semantics): per layer
//   h = x @ W ; out[v] = dinv[v]*(dinv[v]*h[v] + sum_e dinv[s]*h[s]) + b
// CSR + dinv built once (edge structure shared by all 3 layers).
// Edge payload stored as int2 {src, bits(dinv[src])} -> 1 line per edge scatter.
// Aggregation gathers 2 rows (128f) / 4 rows (64f) per dwordx4 instruction.
// ---------------------------------------------------------------------------

#define NFEAT_IN 128
#define SCAN_CHUNK 2048

__global__ void count_kernel(const int* __restrict__ dst, int* __restrict__ cnt, int E) {
    int i = blockIdx.x * blockDim.x + threadIdx.x;
    int base = i * 4;
    if (base + 4 <= E) {
        int4 d = *(const int4*)&dst[base];
        atomicAdd(&cnt[d.x], 1);
        atomicAdd(&cnt[d.y], 1);
        atomicAdd(&cnt[d.z], 1);
        atomicAdd(&cnt[d.w], 1);
    } else {
        for (int k = base; k < E; ++k) atomicAdd(&cnt[dst[k]], 1);
    }
}

// pass 1: per-chunk reduction -> bsum[b]
__global__ __launch_bounds__(256) void reduce_kernel(const int* __restrict__ cnt,
                                                     int* __restrict__ bsum, int n) {
    __shared__ int wtot[4];
    int b = blockIdx.x, t = threadIdx.x;
    int base = b * SCAN_CHUNK + t * 8;
    int s = 0;
    if (base + 8 <= n) {
        int4 a = *(const int4*)&cnt[base];
        int4 c = *(const int4*)&cnt[base + 4];
        s = a.x + a.y + a.z + a.w + c.x + c.y + c.z + c.w;
    } else {
        for (int i = 0; i < 8; ++i) if (base + i < n) s += cnt[base + i];
    }
    int lane = t & 63, wid = t >> 6;
    #pragma unroll
    for (int off = 32; off > 0; off >>= 1) s += __shfl_down(s, off, 64);
    if (lane == 0) wtot[wid] = s;
    __syncthreads();
    if (t == 0) bsum[b] = wtot[0] + wtot[1] + wtot[2] + wtot[3];
}

// pass 2: single-wave scan of block sums (nb <= 64); bsum becomes exclusive base
__global__ void scanb_kernel(int* __restrict__ bsum, int nb, int* __restrict__ offs, int n) {
    int lane = threadIdx.x;
    int v = (lane < nb) ? bsum[lane] : 0;
    int inc = v;
    #pragma unroll
    for (int off = 1; off < 64; off <<= 1) {
        int t = __shfl_up(inc, off, 64);
        if (lane >= off) inc += t;
    }
    if (lane < nb) bsum[lane] = inc - v;  // exclusive
    if (lane == 63) offs[n] = inc;        // total
}

// pass 3: local scan within chunk; write offs, pos (=offs copy), dinv
__global__ __launch_bounds__(256) void scan3_kernel(const int* __restrict__ cnt,
                                                    const int* __restrict__ bbase,
                                                    int* __restrict__ offs,
                                                    int* __restrict__ pos,
                                                    float* __restrict__ dinv, int n) {
    __shared__ int wtot[4];
    int b = blockIdx.x, t = threadIdx.x;
    int base = b * SCAN_CHUNK + t * 8;
    int v[8];
    #pragma unroll
    for (int i = 0; i < 8; ++i) v[i] = (base + i < n) ? cnt[base + i] : 0;
    int psum[8], s = 0;
    #pragma unroll
    for (int i = 0; i < 8; ++i) { psum[i] = s; s += v[i]; }
    int lane = t & 63, wid = t >> 6;
    int inc = s;
    #pragma unroll
    for (int off = 1; off < 64; off <<= 1) {
        int tt = __shfl_up(inc, off, 64);
        if (lane >= off) inc += tt;
    }
    if (lane == 63) wtot[wid] = inc;
    __syncthreads();
    int wb = 0;
    for (int w = 0; w < wid; ++w) wb += wtot[w];
    int tbase = bbase[b] + wb + (inc - s);
    #pragma unroll
    for (int i = 0; i < 8; ++i) {
        if (base + i < n) {
            int o = tbase + psum[i];
            offs[base + i] = o;
            pos[base + i] = o;
            dinv[base + i] = rsqrtf((float)(v[i] + 1));  // +1 self-loop
        }
    }
}

__global__ void fill_kernel(const int* __restrict__ src, const int* __restrict__ dst,
                            int* __restrict__ pos, const float* __restrict__ dinv,
                            int2* __restrict__ esw, int E) {
    int i = blockIdx.x * blockDim.x + threadIdx.x;
    if (i >= E) return;
    int d = dst[i];
    int s = src[i];
    int p = atomicAdd(&pos[d], 1);
    int2 e;
    e.x = s;
    e.y = __float_as_int(dinv[s]);
    esw[p] = e;  // single 8B scatter: one cache line per edge
}

// fp32 GEMM  Y[nrows,BN] = X[nrows,128] @ W[128,BN];  BM=64, BK=32
template <int BN>
__global__ __launch_bounds__(256) void gemm_kernel(const float* __restrict__ X,
                                                   const float* __restrict__ W,
                                                   float* __restrict__ Y, int nrows) {
    constexpr int K = 128, BM = 64, BK = 32;
    constexpr int JJ = BN / 16;
    __shared__ float Xs[BK][BM];
    __shared__ float Ws[BK * BN];
    int t = threadIdx.x;
    int tx = t & 15, ty = t >> 4;
    int blockRow = blockIdx.x * BM;
    float acc[4][JJ];
    #pragma unroll
    for (int r = 0; r < 4; ++r)
        #pragma unroll
        for (int j = 0; j < JJ; ++j) acc[r][j] = 0.f;

    for (int kt = 0; kt < K; kt += BK) {
        {
            int row = t >> 2;
            int c = (t & 3) * 8;
            int gr = blockRow + row;
            float4 a, d4;
            if (gr < nrows) {
                a  = *(const float4*)&X[(size_t)gr * K + kt + c];
                d4 = *(const float4*)&X[(size_t)gr * K + kt + c + 4];
            } else {
                a.x=a.y=a.z=a.w=0.f; d4=a;
            }
            Xs[c + 0][row] = a.x;  Xs[c + 1][row] = a.y;
            Xs[c + 2][row] = a.z;  Xs[c + 3][row] = a.w;
            Xs[c + 4][row] = d4.x; Xs[c + 5][row] = d4.y;
            Xs[c + 6][row] = d4.z; Xs[c + 7][row] = d4.w;
        }
        for (int i = t * 4; i < BK * BN; i += 256 * 4)
            *(float4*)&Ws[i] = *(const float4*)&W[(size_t)kt * BN + i];
        __syncthreads();
        #pragma unroll 4
        for (int k = 0; k < BK; ++k) {
            float4 xa = *(const float4*)&Xs[k][ty * 4];
            float wv[JJ];
            #pragma unroll
            for (int j = 0; j < JJ; ++j) wv[j] = Ws[k * BN + tx + 16 * j];
            #pragma unroll
            for (int j = 0; j < JJ; ++j) {
                acc[0][j] += xa.x * wv[j];
                acc[1][j] += xa.y * wv[j];
                acc[2][j] += xa.z * wv[j];
                acc[3][j] += xa.w * wv[j];
            }
        }
        __syncthreads();
    }
    #pragma unroll
    for (int r = 0; r < 4; ++r) {
        int gr = blockRow + ty * 4 + r;
        if (gr < nrows) {
            #pragma unroll
            for (int j = 0; j < JJ; ++j)
                Y[(size_t)gr * BN + tx + 16 * j] = acc[r][j];
        }
    }
}

// CSR aggregation, NF=128: one wave per node. Lane halves cover 2 edges per
// dwordx4 gather (1024B/instr); 4 gathers (8 edges) in flight; clamp+mask tail.
template <bool ELU>
__global__ __launch_bounds__(256) void agg128_kernel(const float* __restrict__ H,
                                                     const int* __restrict__ offs,
                                                     const int2* __restrict__ esw,
                                                     const float* __restrict__ dinv,
                                                     const float* __restrict__ bias,
                                                     float* __restrict__ out, int n) {
    int lane = threadIdx.x & 63;
    int half = lane >> 5;       // which edge of the pair
    int fl = lane & 31;         // feature block: feats fl*4 .. fl*4+3
    int v = blockIdx.x * 4 + (threadIdx.x >> 6);
    if (v >= n) return;
    float dv = dinv[v];
    int e0 = offs[v], e1 = offs[v + 1];
    float ax = 0.f, ay = 0.f, az = 0.f, aw = 0.f;
    int elast = e1 - 1;
    for (int base = e0 + half; base < e1; base += 8) {
        #pragma unroll
        for (int j = 0; j < 4; ++j) {
            int e = base + 2 * j;
            bool ok = (e < e1);
            int ec = ok ? e : elast;
            int2 p = esw[ec];
            float w = ok ? __int_as_float(p.y) : 0.f;
            float4 h = *(const float4*)&H[(size_t)p.x * 128 + fl * 4];
            ax += w * h.x; ay += w * h.y; az += w * h.z; aw += w * h.w;
        }
    }
    // combine the two halves (lane ^ 32)
    ax += __shfl(ax, lane ^ 32, 64);
    ay += __shfl(ay, lane ^ 32, 64);
    az += __shfl(az, lane ^ 32, 64);
    aw += __shfl(aw, lane ^ 32, 64);
    // self loop + norm + bias
    float4 hv = *(const float4*)&H[(size_t)v * 128 + fl * 4];
    float4 bb = *(const float4*)&bias[fl * 4];
    float rx = dv * (ax + dv * hv.x) + bb.x;
    float ry = dv * (ay + dv * hv.y) + bb.y;
    float rz = dv * (az + dv * hv.z) + bb.z;
    float rw = dv * (aw + dv * hv.w) + bb.w;
    if (ELU) {
        rx = rx > 0.f ? rx : expm1f(rx);
        ry = ry > 0.f ? ry : expm1f(ry);
        rz = rz > 0.f ? rz : expm1f(rz);
        rw = rw > 0.f ? rw : expm1f(rw);
    }
    if (half == 0) {
        float4 r; r.x = rx; r.y = ry; r.z = rz; r.w = rw;
        *(float4*)&out[(size_t)v * 128 + fl * 4] = r;
    }
}

// CSR aggregation, NF=64: lane quarters cover 4 edges per dwordx4 gather;
// 2x unroll = 8 edges in flight; xor-combine over quarters.
template <bool ELU>
__global__ __launch_bounds__(256) void agg64_kernel(const float* __restrict__ H,
                                                    const int* __restrict__ offs,
                                                    const int2* __restrict__ esw,
                                                    const float* __restrict__ dinv,
                                                    const float* __restrict__ bias,
                                                    float* __restrict__ out, int n) {
    int lane = threadIdx.x & 63;
    int quarter = lane >> 4;
    int fl = lane & 15;         // feature block: feats fl*4 .. fl*4+3
    int v = blockIdx.x * 4 + (threadIdx.x >> 6);
    if (v >= n) return;
    float dv = dinv[v];
    int e0 = offs[v], e1 = offs[v + 1];
    float ax = 0.f, ay = 0.f, az = 0.f, aw = 0.f;
    int elast = e1 - 1;
    for (int base = e0 + quarter; base < e1; base += 8) {
        #pragma unroll
        for (int j = 0; j < 2; ++j) {
            int e = base + 4 * j;
            bool ok = (e < e1);
            int ec = ok ? e : elast;
            int2 p = esw[ec];
            float w = ok ? __int_as_float(p.y) : 0.f;
            float4 h = *(const float4*)&H[(size_t)p.x * 64 + fl * 4];
            ax += w * h.x; ay += w * h.y; az += w * h.z; aw += w * h.w;
        }
    }
    #pragma unroll
    for (int m = 16; m <= 32; m <<= 1) {
        ax += __shfl(ax, lane ^ m, 64);
        ay += __shfl(ay, lane ^ m, 64);
        az += __shfl(az, lane ^ m, 64);
        aw += __shfl(aw, lane ^ m, 64);
    }
    float4 hv = *(const float4*)&H[(size_t)v * 64 + fl * 4];
    float4 bb = *(const float4*)&bias[fl * 4];
    float rx = dv * (ax + dv * hv.x) + bb.x;
    float ry = dv * (ay + dv * hv.y) + bb.y;
    float rz = dv * (az + dv * hv.z) + bb.z;
    float rw = dv * (aw + dv * hv.w) + bb.w;
    if (ELU) {
        rx = rx > 0.f ? rx : expm1f(rx);
        ry = ry > 0.f ? ry : expm1f(ry);
        rz = rz > 0.f ? rz : expm1f(rz);
        rw = rw > 0.f ? rw : expm1f(rw);
    }
    if (quarter == 0) {
        float4 r; r.x = rx; r.y = ry; r.z = rz; r.w = rw;
        *(float4*)&out[(size_t)v * 64 + fl * 4] = r;
    }
}

static inline size_t alignup(size_t x) { return (x + 255) & ~(size_t)255; }

extern "C" void kernel_launch(void* const* d_in, const int* in_sizes, int n_in,
                              void* d_out, int out_size, void* d_ws, size_t ws_size,
                              hipStream_t stream) {
    const float* x  = (const float*)d_in[0];
    const int*   ei = (const int*)d_in[1];
    const float* W1 = (const float*)d_in[2];
    const float* b1 = (const float*)d_in[3];
    const float* W2 = (const float*)d_in[4];
    const float* b2 = (const float*)d_in[5];
    const float* W3 = (const float*)d_in[6];
    const float* b3 = (const float*)d_in[7];
    float* out = (float*)d_out;

    const int N = in_sizes[0] / NFEAT_IN;  // 50000
    const int E = in_sizes[1] / 2;         // 800000
    const int* src = ei;
    const int* dst = ei + E;

    // workspace carve
    char* w = (char*)d_ws;
    int* cnt  = (int*)w;  w += alignup((size_t)N * sizeof(int));
    int* pos  = (int*)w;  w += alignup((size_t)N * sizeof(int));
    int* offs = (int*)w;  w += alignup((size_t)(N + 1) * sizeof(int));
    float* dinv = (float*)w; w += alignup((size_t)N * sizeof(float));
    int* bsum = (int*)w;  w += alignup((size_t)64 * sizeof(int));
    int2* esw = (int2*)w; w += alignup((size_t)E * sizeof(int2));
    float* hA = (float*)w; w += alignup((size_t)N * 128 * sizeof(float));
    float* hB = (float*)w; w += alignup((size_t)N * 128 * sizeof(float));

    const int nb = (N + SCAN_CHUNK - 1) / SCAN_CHUNK;  // 25 (<= 64 required)

    // --- build CSR + dinv (shared by all 3 layers) ---
    hipMemsetAsync(cnt, 0, (size_t)N * sizeof(int), stream);
    count_kernel<<<(E / 4 + 255) / 256, 256, 0, stream>>>(dst, cnt, E);
    reduce_kernel<<<nb, 256, 0, stream>>>(cnt, bsum, N);
    scanb_kernel<<<1, 64, 0, stream>>>(bsum, nb, offs, N);
    scan3_kernel<<<nb, 256, 0, stream>>>(cnt, bsum, offs, pos, dinv, N);
    fill_kernel<<<(E + 255) / 256, 256, 0, stream>>>(src, dst, pos, dinv, esw, E);

    int gemm_grid = (N + 63) / 64;
    int agg_grid = (N + 3) / 4;

    // layer 1
    gemm_kernel<128><<<gemm_grid, 256, 0, stream>>>(x, W1, hA, N);
    agg128_kernel<true><<<agg_grid, 256, 0, stream>>>(hA, offs, esw, dinv, b1, hB, N);
    // layer 2
    gemm_kernel<128><<<gemm_grid, 256, 0, stream>>>(hB, W2, hA, N);
    agg128_kernel<true><<<agg_grid, 256, 0, stream>>>(hA, offs, esw, dinv, b2, hB, N);
    // layer 3 (128 -> 64), no ELU
    gemm_kernel<64><<<gemm_grid, 256, 0, stream>>>(hB, W3, hA, N);
    agg64_kernel<false><<<agg_grid, 256, 0, stream>>>(hA, offs, esw, dinv, b3, out, N);
}

// Round 4
// 298.891 us; speedup vs baseline: 1.8065x; 1.1853x over previous
//
#include <hip/hip_runtime.h>
#include <hip/hip_fp16.h>
#include <math.h>

// ---------------------------------------------------------------------------
// 3-layer GCN (PyG GCNConv semantics): per layer
//   h = x @ W ; out[v] = dinv[v]*(dinv[v]*h[v] + sum_e dinv[s]*h[s]) + b
// CSR + dinv built once. Hidden h stored FP16 (gather traffic halves);
// GEMM accumulates fp32, converts at store via LDS repack. Agg gathers 16B
// of fp16 per lane (8 feats), fp32 accumulate (v_fma_mix).
// ---------------------------------------------------------------------------

#define NFEAT_IN 128
#define SCAN_CHUNK 2048

__global__ void count_kernel(const int* __restrict__ dst, int* __restrict__ cnt, int E) {
    int i = blockIdx.x * blockDim.x + threadIdx.x;
    int base = i * 4;
    if (base + 4 <= E) {
        int4 d = *(const int4*)&dst[base];
        atomicAdd(&cnt[d.x], 1);
        atomicAdd(&cnt[d.y], 1);
        atomicAdd(&cnt[d.z], 1);
        atomicAdd(&cnt[d.w], 1);
    } else {
        for (int k = base; k < E; ++k) atomicAdd(&cnt[dst[k]], 1);
    }
}

__global__ __launch_bounds__(256) void reduce_kernel(const int* __restrict__ cnt,
                                                     int* __restrict__ bsum, int n) {
    __shared__ int wtot[4];
    int b = blockIdx.x, t = threadIdx.x;
    int base = b * SCAN_CHUNK + t * 8;
    int s = 0;
    if (base + 8 <= n) {
        int4 a = *(const int4*)&cnt[base];
        int4 c = *(const int4*)&cnt[base + 4];
        s = a.x + a.y + a.z + a.w + c.x + c.y + c.z + c.w;
    } else {
        for (int i = 0; i < 8; ++i) if (base + i < n) s += cnt[base + i];
    }
    int lane = t & 63, wid = t >> 6;
    #pragma unroll
    for (int off = 32; off > 0; off >>= 1) s += __shfl_down(s, off, 64);
    if (lane == 0) wtot[wid] = s;
    __syncthreads();
    if (t == 0) bsum[b] = wtot[0] + wtot[1] + wtot[2] + wtot[3];
}

__global__ void scanb_kernel(int* __restrict__ bsum, int nb, int* __restrict__ offs, int n) {
    int lane = threadIdx.x;
    int v = (lane < nb) ? bsum[lane] : 0;
    int inc = v;
    #pragma unroll
    for (int off = 1; off < 64; off <<= 1) {
        int t = __shfl_up(inc, off, 64);
        if (lane >= off) inc += t;
    }
    if (lane < nb) bsum[lane] = inc - v;  // exclusive
    if (lane == 63) offs[n] = inc;        // total
}

__global__ __launch_bounds__(256) void scan3_kernel(const int* __restrict__ cnt,
                                                    const int* __restrict__ bbase,
                                                    int* __restrict__ offs,
                                                    int* __restrict__ pos,
                                                    float* __restrict__ dinv, int n) {
    __shared__ int wtot[4];
    int b = blockIdx.x, t = threadIdx.x;
    int base = b * SCAN_CHUNK + t * 8;
    int v[8];
    #pragma unroll
    for (int i = 0; i < 8; ++i) v[i] = (base + i < n) ? cnt[base + i] : 0;
    int psum[8], s = 0;
    #pragma unroll
    for (int i = 0; i < 8; ++i) { psum[i] = s; s += v[i]; }
    int lane = t & 63, wid = t >> 6;
    int inc = s;
    #pragma unroll
    for (int off = 1; off < 64; off <<= 1) {
        int tt = __shfl_up(inc, off, 64);
        if (lane >= off) inc += tt;
    }
    if (lane == 63) wtot[wid] = inc;
    __syncthreads();
    int wb = 0;
    for (int w = 0; w < wid; ++w) wb += wtot[w];
    int tbase = bbase[b] + wb + (inc - s);
    #pragma unroll
    for (int i = 0; i < 8; ++i) {
        if (base + i < n) {
            int o = tbase + psum[i];
            offs[base + i] = o;
            pos[base + i] = o;
            dinv[base + i] = rsqrtf((float)(v[i] + 1));  // +1 self-loop
        }
    }
}

__global__ void fill_kernel(const int* __restrict__ src, const int* __restrict__ dst,
                            int* __restrict__ pos, const float* __restrict__ dinv,
                            int2* __restrict__ esw, int E) {
    int i = blockIdx.x * blockDim.x + threadIdx.x;
    if (i >= E) return;
    int d = dst[i];
    int s = src[i];
    int p = atomicAdd(&pos[d], 1);
    int2 e;
    e.x = s;
    e.y = __float_as_int(dinv[s]);
    esw[p] = e;  // single 8B scatter: one cache line per edge
}

// fp32 GEMM  Y[nrows,BN](fp16) = X[nrows,128] @ W[128,BN];  BM=64, BK=32
// fp32 accumulate; epilogue repacks through LDS (reusing Ws) for coalesced
// 16B fp16 stores.
template <int BN>
__global__ __launch_bounds__(256) void gemm_kernel(const float* __restrict__ X,
                                                   const float* __restrict__ W,
                                                   __half* __restrict__ Y, int nrows) {
    constexpr int K = 128, BM = 64, BK = 32;
    constexpr int JJ = BN / 16;
    __shared__ float Xs[BK][BM];
    __shared__ float Ws[BK * BN];
    int t = threadIdx.x;
    int tx = t & 15, ty = t >> 4;
    int blockRow = blockIdx.x * BM;
    float acc[4][JJ];
    #pragma unroll
    for (int r = 0; r < 4; ++r)
        #pragma unroll
        for (int j = 0; j < JJ; ++j) acc[r][j] = 0.f;

    for (int kt = 0; kt < K; kt += BK) {
        {
            int row = t >> 2;
            int c = (t & 3) * 8;
            int gr = blockRow + row;
            float4 a, d4;
            if (gr < nrows) {
                a  = *(const float4*)&X[(size_t)gr * K + kt + c];
                d4 = *(const float4*)&X[(size_t)gr * K + kt + c + 4];
            } else {
                a.x=a.y=a.z=a.w=0.f; d4=a;
            }
            Xs[c + 0][row] = a.x;  Xs[c + 1][row] = a.y;
            Xs[c + 2][row] = a.z;  Xs[c + 3][row] = a.w;
            Xs[c + 4][row] = d4.x; Xs[c + 5][row] = d4.y;
            Xs[c + 6][row] = d4.z; Xs[c + 7][row] = d4.w;
        }
        for (int i = t * 4; i < BK * BN; i += 256 * 4)
            *(float4*)&Ws[i] = *(const float4*)&W[(size_t)kt * BN + i];
        __syncthreads();
        #pragma unroll 4
        for (int k = 0; k < BK; ++k) {
            float4 xa = *(const float4*)&Xs[k][ty * 4];
            float wv[JJ];
            #pragma unroll
            for (int j = 0; j < JJ; ++j) wv[j] = Ws[k * BN + tx + 16 * j];
            #pragma unroll
            for (int j = 0; j < JJ; ++j) {
                acc[0][j] += xa.x * wv[j];
                acc[1][j] += xa.y * wv[j];
                acc[2][j] += xa.z * wv[j];
                acc[3][j] += xa.w * wv[j];
            }
        }
        __syncthreads();
    }
    // epilogue: fp16 repack through LDS (Ws reused; BM*BN*2 <= BK*BN*4)
    __half* Hs = (__half*)Ws;
    #pragma unroll
    for (int r = 0; r < 4; ++r)
        #pragma unroll
        for (int j = 0; j < JJ; ++j)
            Hs[(ty * 4 + r) * BN + tx + 16 * j] = __float2half_rn(acc[r][j]);
    __syncthreads();
    for (int i = t * 8; i < BM * BN; i += 256 * 8) {
        int gr = blockRow + i / BN;
        if (gr < nrows)
            *(float4*)&Y[(size_t)blockRow * BN + i] = *(const float4*)&Hs[i];
    }
}

// CSR aggregation, NF=128 fp16 rows (256B). Quarter-wave per edge: 4 edges per
// dwordx4 gather instruction, 4x unroll = 16 edges in flight. fp32 accumulate.
template <bool ELU>
__global__ __launch_bounds__(256) void agg128_kernel(const __half* __restrict__ H,
                                                     const int* __restrict__ offs,
                                                     const int2* __restrict__ esw,
                                                     const float* __restrict__ dinv,
                                                     const float* __restrict__ bias,
                                                     float* __restrict__ out, int n) {
    int lane = threadIdx.x & 63;
    int q = lane >> 4;          // edge slot 0..3
    int fl = lane & 15;         // feature block: feats fl*8 .. fl*8+7
    int v = blockIdx.x * 4 + (threadIdx.x >> 6);
    if (v >= n) return;
    float dv = dinv[v];
    int e0 = offs[v], e1 = offs[v + 1];
    float a0=0.f,a1=0.f,a2=0.f,a3=0.f,a4=0.f,a5=0.f,a6=0.f,a7=0.f;
    int elast = e1 - 1;
    for (int base = e0 + q; base < e1; base += 16) {
        #pragma unroll
        for (int j = 0; j < 4; ++j) {
            int e = base + 4 * j;
            bool ok = (e < e1);
            int ec = ok ? e : elast;
            int2 p = esw[ec];
            float w = ok ? __int_as_float(p.y) : 0.f;
            uint4 hq = *(const uint4*)(H + (size_t)p.x * 128 + fl * 8);
            const __half2* hp = (const __half2*)&hq;
            float2 f0 = __half22float2(hp[0]);
            float2 f1 = __half22float2(hp[1]);
            float2 f2 = __half22float2(hp[2]);
            float2 f3 = __half22float2(hp[3]);
            a0 += w * f0.x; a1 += w * f0.y;
            a2 += w * f1.x; a3 += w * f1.y;
            a4 += w * f2.x; a5 += w * f2.y;
            a6 += w * f3.x; a7 += w * f3.y;
        }
    }
    // combine the four quarters
    #pragma unroll
    for (int m = 16; m <= 32; m <<= 1) {
        a0 += __shfl_xor(a0, m, 64); a1 += __shfl_xor(a1, m, 64);
        a2 += __shfl_xor(a2, m, 64); a3 += __shfl_xor(a3, m, 64);
        a4 += __shfl_xor(a4, m, 64); a5 += __shfl_xor(a5, m, 64);
        a6 += __shfl_xor(a6, m, 64); a7 += __shfl_xor(a7, m, 64);
    }
    if (q == 0) {
        uint4 hq = *(const uint4*)(H + (size_t)v * 128 + fl * 8);
        const __half2* hp = (const __half2*)&hq;
        float2 s0 = __half22float2(hp[0]);
        float2 s1 = __half22float2(hp[1]);
        float2 s2 = __half22float2(hp[2]);
        float2 s3 = __half22float2(hp[3]);
        float4 b0 = *(const float4*)&bias[fl * 8];
        float4 b1 = *(const float4*)&bias[fl * 8 + 4];
        float r0 = dv * (a0 + dv * s0.x) + b0.x;
        float r1 = dv * (a1 + dv * s0.y) + b0.y;
        float r2 = dv * (a2 + dv * s1.x) + b0.z;
        float r3 = dv * (a3 + dv * s1.y) + b0.w;
        float r4 = dv * (a4 + dv * s2.x) + b1.x;
        float r5 = dv * (a5 + dv * s2.y) + b1.y;
        float r6 = dv * (a6 + dv * s3.x) + b1.z;
        float r7 = dv * (a7 + dv * s3.y) + b1.w;
        if (ELU) {
            r0 = r0 > 0.f ? r0 : expm1f(r0);
            r1 = r1 > 0.f ? r1 : expm1f(r1);
            r2 = r2 > 0.f ? r2 : expm1f(r2);
            r3 = r3 > 0.f ? r3 : expm1f(r3);
            r4 = r4 > 0.f ? r4 : expm1f(r4);
            r5 = r5 > 0.f ? r5 : expm1f(r5);
            r6 = r6 > 0.f ? r6 : expm1f(r6);
            r7 = r7 > 0.f ? r7 : expm1f(r7);
        }
        float4 o0; o0.x = r0; o0.y = r1; o0.z = r2; o0.w = r3;
        float4 o1; o1.x = r4; o1.y = r5; o1.z = r6; o1.w = r7;
        *(float4*)&out[(size_t)v * 128 + fl * 8] = o0;
        *(float4*)&out[(size_t)v * 128 + fl * 8 + 4] = o1;
    }
}

// CSR aggregation, NF=64 fp16 rows (128B). Eighth-wave per edge: 8 edges per
// gather instruction, 2x unroll = 16 edges in flight.
template <bool ELU>
__global__ __launch_bounds__(256) void agg64_kernel(const __half* __restrict__ H,
                                                    const int* __restrict__ offs,
                                                    const int2* __restrict__ esw,
                                                    const float* __restrict__ dinv,
                                                    const float* __restrict__ bias,
                                                    float* __restrict__ out, int n) {
    int lane = threadIdx.x & 63;
    int q = lane >> 3;          // edge slot 0..7
    int fl = lane & 7;          // feature block: feats fl*8 .. fl*8+7
    int v = blockIdx.x * 4 + (threadIdx.x >> 6);
    if (v >= n) return;
    float dv = dinv[v];
    int e0 = offs[v], e1 = offs[v + 1];
    float a0=0.f,a1=0.f,a2=0.f,a3=0.f,a4=0.f,a5=0.f,a6=0.f,a7=0.f;
    int elast = e1 - 1;
    for (int base = e0 + q; base < e1; base += 16) {
        #pragma unroll
        for (int j = 0; j < 2; ++j) {
            int e = base + 8 * j;
            bool ok = (e < e1);
            int ec = ok ? e : elast;
            int2 p = esw[ec];
            float w = ok ? __int_as_float(p.y) : 0.f;
            uint4 hq = *(const uint4*)(H + (size_t)p.x * 64 + fl * 8);
            const __half2* hp = (const __half2*)&hq;
            float2 f0 = __half22float2(hp[0]);
            float2 f1 = __half22float2(hp[1]);
            float2 f2 = __half22float2(hp[2]);
            float2 f3 = __half22float2(hp[3]);
            a0 += w * f0.x; a1 += w * f0.y;
            a2 += w * f1.x; a3 += w * f1.y;
            a4 += w * f2.x; a5 += w * f2.y;
            a6 += w * f3.x; a7 += w * f3.y;
        }
    }
    #pragma unroll
    for (int m = 8; m <= 32; m <<= 1) {
        a0 += __shfl_xor(a0, m, 64); a1 += __shfl_xor(a1, m, 64);
        a2 += __shfl_xor(a2, m, 64); a3 += __shfl_xor(a3, m, 64);
        a4 += __shfl_xor(a4, m, 64); a5 += __shfl_xor(a5, m, 64);
        a6 += __shfl_xor(a6, m, 64); a7 += __shfl_xor(a7, m, 64);
    }
    if (q == 0) {
        uint4 hq = *(const uint4*)(H + (size_t)v * 64 + fl * 8);
        const __half2* hp = (const __half2*)&hq;
        float2 s0 = __half22float2(hp[0]);
        float2 s1 = __half22float2(hp[1]);
        float2 s2 = __half22float2(hp[2]);
        float2 s3 = __half22float2(hp[3]);
        float4 b0 = *(const float4*)&bias[fl * 8];
        float4 b1 = *(const float4*)&bias[fl * 8 + 4];
        float r0 = dv * (a0 + dv * s0.x) + b0.x;
        float r1 = dv * (a1 + dv * s0.y) + b0.y;
        float r2 = dv * (a2 + dv * s1.x) + b0.z;
        float r3 = dv * (a3 + dv * s1.y) + b0.w;
        float r4 = dv * (a4 + dv * s2.x) + b1.x;
        float r5 = dv * (a5 + dv * s2.y) + b1.y;
        float r6 = dv * (a6 + dv * s3.x) + b1.z;
        float r7 = dv * (a7 + dv * s3.y) + b1.w;
        if (ELU) {
            r0 = r0 > 0.f ? r0 : expm1f(r0);
            r1 = r1 > 0.f ? r1 : expm1f(r1);
            r2 = r2 > 0.f ? r2 : expm1f(r2);
            r3 = r3 > 0.f ? r3 : expm1f(r3);
            r4 = r4 > 0.f ? r4 : expm1f(r4);
            r5 = r5 > 0.f ? r5 : expm1f(r5);
            r6 = r6 > 0.f ? r6 : expm1f(r6);
            r7 = r7 > 0.f ? r7 : expm1f(r7);
        }
        float4 o0; o0.x = r0; o0.y = r1; o0.z = r2; o0.w = r3;
        float4 o1; o1.x = r4; o1.y = r5; o1.z = r6; o1.w = r7;
        *(float4*)&out[(size_t)v * 64 + fl * 8] = o0;
        *(float4*)&out[(size_t)v * 64 + fl * 8 + 4] = o1;
    }
}

static inline size_t alignup(size_t x) { return (x + 255) & ~(size_t)255; }

extern "C" void kernel_launch(void* const* d_in, const int* in_sizes, int n_in,
                              void* d_out, int out_size, void* d_ws, size_t ws_size,
                              hipStream_t stream) {
    const float* x  = (const float*)d_in[0];
    const int*   ei = (const int*)d_in[1];
    const float* W1 = (const float*)d_in[2];
    const float* b1 = (const float*)d_in[3];
    const float* W2 = (const float*)d_in[4];
    const float* b2 = (const float*)d_in[5];
    const float* W3 = (const float*)d_in[6];
    const float* b3 = (const float*)d_in[7];
    float* out = (float*)d_out;

    const int N = in_sizes[0] / NFEAT_IN;  // 50000
    const int E = in_sizes[1] / 2;         // 800000
    const int* src = ei;
    const int* dst = ei + E;

    // workspace carve
    char* w = (char*)d_ws;
    int* cnt  = (int*)w;  w += alignup((size_t)N * sizeof(int));
    int* pos  = (int*)w;  w += alignup((size_t)N * sizeof(int));
    int* offs = (int*)w;  w += alignup((size_t)(N + 1) * sizeof(int));
    float* dinv = (float*)w; w += alignup((size_t)N * sizeof(float));
    int* bsum = (int*)w;  w += alignup((size_t)64 * sizeof(int));
    int2* esw = (int2*)w; w += alignup((size_t)E * sizeof(int2));
    __half* hH = (__half*)w; w += alignup((size_t)N * 128 * sizeof(__half));
    float* xA = (float*)w;   w += alignup((size_t)N * 128 * sizeof(float));

    const int nb = (N + SCAN_CHUNK - 1) / SCAN_CHUNK;  // 25 (<= 64 required)

    // --- build CSR + dinv (shared by all 3 layers) ---
    hipMemsetAsync(cnt, 0, (size_t)N * sizeof(int), stream);
    count_kernel<<<(E / 4 + 255) / 256, 256, 0, stream>>>(dst, cnt, E);
    reduce_kernel<<<nb, 256, 0, stream>>>(cnt, bsum, N);
    scanb_kernel<<<1, 64, 0, stream>>>(bsum, nb, offs, N);
    scan3_kernel<<<nb, 256, 0, stream>>>(cnt, bsum, offs, pos, dinv, N);
    fill_kernel<<<(E + 255) / 256, 256, 0, stream>>>(src, dst, pos, dinv, esw, E);

    int gemm_grid = (N + 63) / 64;
    int agg_grid = (N + 3) / 4;

    // layer 1
    gemm_kernel<128><<<gemm_grid, 256, 0, stream>>>(x, W1, hH, N);
    agg128_kernel<true><<<agg_grid, 256, 0, stream>>>(hH, offs, esw, dinv, b1, xA, N);
    // layer 2
    gemm_kernel<128><<<gemm_grid, 256, 0, stream>>>(xA, W2, hH, N);
    agg128_kernel<true><<<agg_grid, 256, 0, stream>>>(hH, offs, esw, dinv, b2, xA, N);
    // layer 3 (128 -> 64), no ELU
    gemm_kernel<64><<<gemm_grid, 256, 0, stream>>>(xA, W3, hH, N);
    agg64_kernel<false><<<agg_grid, 256, 0, stream>>>(hH, offs, esw, dinv, b3, out, N);
}

// Round 5
// 289.920 us; speedup vs baseline: 1.8624x; 1.0309x over previous
//
#include <hip/hip_runtime.h>
#include <hip/hip_fp16.h>
#include <math.h>

// ---------------------------------------------------------------------------
// 3-layer GCN (PyG GCNConv semantics): per layer
//   h = x @ W ; out[v] = dinv[v]*(dinv[v]*h[v] + sum_e dinv[s]*h[s]) + b
// CSR + dinv built once. Hidden h stored FP16. Fill is dst-sharded 8-way so
// each esw cache line is written by blocks on a single XCD (kills the ~8x
// cross-XCD write amplification seen in round 4: WRITE_SIZE 52.9MB for 6.4MB
// payload).
// ---------------------------------------------------------------------------

#define NFEAT_IN 128
#define SCAN_CHUNK 2048
#define NSHARD 8

__global__ void count_kernel(const int* __restrict__ dst, int* __restrict__ cnt, int E) {
    int i = blockIdx.x * blockDim.x + threadIdx.x;
    int base = i * 4;
    if (base + 4 <= E) {
        int4 d = *(const int4*)&dst[base];
        atomicAdd(&cnt[d.x], 1);
        atomicAdd(&cnt[d.y], 1);
        atomicAdd(&cnt[d.z], 1);
        atomicAdd(&cnt[d.w], 1);
    } else {
        for (int k = base; k < E; ++k) atomicAdd(&cnt[dst[k]], 1);
    }
}

__global__ __launch_bounds__(256) void reduce_kernel(const int* __restrict__ cnt,
                                                     int* __restrict__ bsum, int n) {
    __shared__ int wtot[4];
    int b = blockIdx.x, t = threadIdx.x;
    int base = b * SCAN_CHUNK + t * 8;
    int s = 0;
    if (base + 8 <= n) {
        int4 a = *(const int4*)&cnt[base];
        int4 c = *(const int4*)&cnt[base + 4];
        s = a.x + a.y + a.z + a.w + c.x + c.y + c.z + c.w;
    } else {
        for (int i = 0; i < 8; ++i) if (base + i < n) s += cnt[base + i];
    }
    int lane = t & 63, wid = t >> 6;
    #pragma unroll
    for (int off = 32; off > 0; off >>= 1) s += __shfl_down(s, off, 64);
    if (lane == 0) wtot[wid] = s;
    __syncthreads();
    if (t == 0) bsum[b] = wtot[0] + wtot[1] + wtot[2] + wtot[3];
}

__global__ void scanb_kernel(int* __restrict__ bsum, int nb, int* __restrict__ offs, int n) {
    int lane = threadIdx.x;
    int v = (lane < nb) ? bsum[lane] : 0;
    int inc = v;
    #pragma unroll
    for (int off = 1; off < 64; off <<= 1) {
        int t = __shfl_up(inc, off, 64);
        if (lane >= off) inc += t;
    }
    if (lane < nb) bsum[lane] = inc - v;  // exclusive
    if (lane == 63) offs[n] = inc;        // total
}

__global__ __launch_bounds__(256) void scan3_kernel(const int* __restrict__ cnt,
                                                    const int* __restrict__ bbase,
                                                    int* __restrict__ offs,
                                                    int* __restrict__ pos,
                                                    float* __restrict__ dinv, int n) {
    __shared__ int wtot[4];
    int b = blockIdx.x, t = threadIdx.x;
    int base = b * SCAN_CHUNK + t * 8;
    int v[8];
    #pragma unroll
    for (int i = 0; i < 8; ++i) v[i] = (base + i < n) ? cnt[base + i] : 0;
    int psum[8], s = 0;
    #pragma unroll
    for (int i = 0; i < 8; ++i) { psum[i] = s; s += v[i]; }
    int lane = t & 63, wid = t >> 6;
    int inc = s;
    #pragma unroll
    for (int off = 1; off < 64; off <<= 1) {
        int tt = __shfl_up(inc, off, 64);
        if (lane >= off) inc += tt;
    }
    if (lane == 63) wtot[wid] = inc;
    __syncthreads();
    int wb = 0;
    for (int w = 0; w < wid; ++w) wb += wtot[w];
    int tbase = bbase[b] + wb + (inc - s);
    #pragma unroll
    for (int i = 0; i < 8; ++i) {
        if (base + i < n) {
            int o = tbase + psum[i];
            offs[base + i] = o;
            pos[base + i] = o;
            dinv[base + i] = rsqrtf((float)(v[i] + 1));  // +1 self-loop
        }
    }
}

// dst-sharded fill: shard = blockIdx&7 (round-robin block->XCD mapping puts
// each dst-range's writers on one XCD -> esw slice is single-L2, written once).
__global__ __launch_bounds__(256) void fill_kernel(const int* __restrict__ src,
                                                   const int* __restrict__ dst,
                                                   int* __restrict__ pos,
                                                   const float* __restrict__ dinv,
                                                   int2* __restrict__ esw,
                                                   int E, int shard_sz) {
    int shard = blockIdx.x & (NSHARD - 1);
    int blk = blockIdx.x >> 3;
    int nblk = gridDim.x >> 3;
    int lo = shard * shard_sz;
    int hi = lo + shard_sz;
    int stride = nblk * blockDim.x;
    for (int i = blk * blockDim.x + threadIdx.x; i < E; i += stride) {
        int d = dst[i];
        if (d >= lo && d < hi) {
            int s = src[i];
            int p = atomicAdd(&pos[d], 1);
            int2 e;
            e.x = s;
            e.y = __float_as_int(dinv[s]);
            esw[p] = e;
        }
    }
}

// fp32 GEMM  Y[nrows,BN](fp16) = X[nrows,128] @ W[128,BN];  BM=64, BK=32
template <int BN>
__global__ __launch_bounds__(256) void gemm_kernel(const float* __restrict__ X,
                                                   const float* __restrict__ W,
                                                   __half* __restrict__ Y, int nrows) {
    constexpr int K = 128, BM = 64, BK = 32;
    constexpr int JJ = BN / 16;
    __shared__ float Xs[BK][BM];
    __shared__ float Ws[BK * BN];
    int t = threadIdx.x;
    int tx = t & 15, ty = t >> 4;
    int blockRow = blockIdx.x * BM;
    float acc[4][JJ];
    #pragma unroll
    for (int r = 0; r < 4; ++r)
        #pragma unroll
        for (int j = 0; j < JJ; ++j) acc[r][j] = 0.f;

    for (int kt = 0; kt < K; kt += BK) {
        {
            int row = t >> 2;
            int c = (t & 3) * 8;
            int gr = blockRow + row;
            float4 a, d4;
            if (gr < nrows) {
                a  = *(const float4*)&X[(size_t)gr * K + kt + c];
                d4 = *(const float4*)&X[(size_t)gr * K + kt + c + 4];
            } else {
                a.x=a.y=a.z=a.w=0.f; d4=a;
            }
            Xs[c + 0][row] = a.x;  Xs[c + 1][row] = a.y;
            Xs[c + 2][row] = a.z;  Xs[c + 3][row] = a.w;
            Xs[c + 4][row] = d4.x; Xs[c + 5][row] = d4.y;
            Xs[c + 6][row] = d4.z; Xs[c + 7][row] = d4.w;
        }
        for (int i = t * 4; i < BK * BN; i += 256 * 4)
            *(float4*)&Ws[i] = *(const float4*)&W[(size_t)kt * BN + i];
        __syncthreads();
        #pragma unroll 4
        for (int k = 0; k < BK; ++k) {
            float4 xa = *(const float4*)&Xs[k][ty * 4];
            float wv[JJ];
            #pragma unroll
            for (int j = 0; j < JJ; ++j) wv[j] = Ws[k * BN + tx + 16 * j];
            #pragma unroll
            for (int j = 0; j < JJ; ++j) {
                acc[0][j] += xa.x * wv[j];
                acc[1][j] += xa.y * wv[j];
                acc[2][j] += xa.z * wv[j];
                acc[3][j] += xa.w * wv[j];
            }
        }
        __syncthreads();
    }
    // epilogue: fp16 repack through LDS (Ws reused)
    __half* Hs = (__half*)Ws;
    #pragma unroll
    for (int r = 0; r < 4; ++r)
        #pragma unroll
        for (int j = 0; j < JJ; ++j)
            Hs[(ty * 4 + r) * BN + tx + 16 * j] = __float2half_rn(acc[r][j]);
    __syncthreads();
    for (int i = t * 8; i < BM * BN; i += 256 * 8) {
        int gr = blockRow + i / BN;
        if (gr < nrows)
            *(float4*)&Y[(size_t)blockRow * BN + i] = *(const float4*)&Hs[i];
    }
}

// CSR aggregation, NF=128 fp16 rows (256B). Quarter-wave per edge: 4 edges per
// dwordx4 gather instruction, 4x unroll = 16 edges in flight. fp32 accumulate.
template <bool ELU>
__global__ __launch_bounds__(256) void agg128_kernel(const __half* __restrict__ H,
                                                     const int* __restrict__ offs,
                                                     const int2* __restrict__ esw,
                                                     const float* __restrict__ dinv,
                                                     const float* __restrict__ bias,
                                                     float* __restrict__ out, int n) {
    int lane = threadIdx.x & 63;
    int q = lane >> 4;          // edge slot 0..3
    int fl = lane & 15;         // feature block: feats fl*8 .. fl*8+7
    int v = blockIdx.x * 4 + (threadIdx.x >> 6);
    if (v >= n) return;
    float dv = dinv[v];
    int e0 = offs[v], e1 = offs[v + 1];
    float a0=0.f,a1=0.f,a2=0.f,a3=0.f,a4=0.f,a5=0.f,a6=0.f,a7=0.f;
    int elast = e1 - 1;
    for (int base = e0 + q; base < e1; base += 16) {
        #pragma unroll
        for (int j = 0; j < 4; ++j) {
            int e = base + 4 * j;
            bool ok = (e < e1);
            int ec = ok ? e : elast;
            int2 p = esw[ec];
            float w = ok ? __int_as_float(p.y) : 0.f;
            uint4 hq = *(const uint4*)(H + (size_t)p.x * 128 + fl * 8);
            const __half2* hp = (const __half2*)&hq;
            float2 f0 = __half22float2(hp[0]);
            float2 f1 = __half22float2(hp[1]);
            float2 f2 = __half22float2(hp[2]);
            float2 f3 = __half22float2(hp[3]);
            a0 += w * f0.x; a1 += w * f0.y;
            a2 += w * f1.x; a3 += w * f1.y;
            a4 += w * f2.x; a5 += w * f2.y;
            a6 += w * f3.x; a7 += w * f3.y;
        }
    }
    #pragma unroll
    for (int m = 16; m <= 32; m <<= 1) {
        a0 += __shfl_xor(a0, m, 64); a1 += __shfl_xor(a1, m, 64);
        a2 += __shfl_xor(a2, m, 64); a3 += __shfl_xor(a3, m, 64);
        a4 += __shfl_xor(a4, m, 64); a5 += __shfl_xor(a5, m, 64);
        a6 += __shfl_xor(a6, m, 64); a7 += __shfl_xor(a7, m, 64);
    }
    if (q == 0) {
        uint4 hq = *(const uint4*)(H + (size_t)v * 128 + fl * 8);
        const __half2* hp = (const __half2*)&hq;
        float2 s0 = __half22float2(hp[0]);
        float2 s1 = __half22float2(hp[1]);
        float2 s2 = __half22float2(hp[2]);
        float2 s3 = __half22float2(hp[3]);
        float4 b0 = *(const float4*)&bias[fl * 8];
        float4 b1 = *(const float4*)&bias[fl * 8 + 4];
        float r0 = dv * (a0 + dv * s0.x) + b0.x;
        float r1 = dv * (a1 + dv * s0.y) + b0.y;
        float r2 = dv * (a2 + dv * s1.x) + b0.z;
        float r3 = dv * (a3 + dv * s1.y) + b0.w;
        float r4 = dv * (a4 + dv * s2.x) + b1.x;
        float r5 = dv * (a5 + dv * s2.y) + b1.y;
        float r6 = dv * (a6 + dv * s3.x) + b1.z;
        float r7 = dv * (a7 + dv * s3.y) + b1.w;
        if (ELU) {
            r0 = r0 > 0.f ? r0 : expm1f(r0);
            r1 = r1 > 0.f ? r1 : expm1f(r1);
            r2 = r2 > 0.f ? r2 : expm1f(r2);
            r3 = r3 > 0.f ? r3 : expm1f(r3);
            r4 = r4 > 0.f ? r4 : expm1f(r4);
            r5 = r5 > 0.f ? r5 : expm1f(r5);
            r6 = r6 > 0.f ? r6 : expm1f(r6);
            r7 = r7 > 0.f ? r7 : expm1f(r7);
        }
        float4 o0; o0.x = r0; o0.y = r1; o0.z = r2; o0.w = r3;
        float4 o1; o1.x = r4; o1.y = r5; o1.z = r6; o1.w = r7;
        *(float4*)&out[(size_t)v * 128 + fl * 8] = o0;
        *(float4*)&out[(size_t)v * 128 + fl * 8 + 4] = o1;
    }
}

// CSR aggregation, NF=64 fp16 rows (128B). Eighth-wave per edge: 8 edges per
// gather instruction, 2x unroll = 16 edges in flight.
template <bool ELU>
__global__ __launch_bounds__(256) void agg64_kernel(const __half* __restrict__ H,
                                                    const int* __restrict__ offs,
                                                    const int2* __restrict__ esw,
                                                    const float* __restrict__ dinv,
                                                    const float* __restrict__ bias,
                                                    float* __restrict__ out, int n) {
    int lane = threadIdx.x & 63;
    int q = lane >> 3;          // edge slot 0..7
    int fl = lane & 7;          // feature block: feats fl*8 .. fl*8+7
    int v = blockIdx.x * 4 + (threadIdx.x >> 6);
    if (v >= n) return;
    float dv = dinv[v];
    int e0 = offs[v], e1 = offs[v + 1];
    float a0=0.f,a1=0.f,a2=0.f,a3=0.f,a4=0.f,a5=0.f,a6=0.f,a7=0.f;
    int elast = e1 - 1;
    for (int base = e0 + q; base < e1; base += 16) {
        #pragma unroll
        for (int j = 0; j < 2; ++j) {
            int e = base + 8 * j;
            bool ok = (e < e1);
            int ec = ok ? e : elast;
            int2 p = esw[ec];
            float w = ok ? __int_as_float(p.y) : 0.f;
            uint4 hq = *(const uint4*)(H + (size_t)p.x * 64 + fl * 8);
            const __half2* hp = (const __half2*)&hq;
            float2 f0 = __half22float2(hp[0]);
            float2 f1 = __half22float2(hp[1]);
            float2 f2 = __half22float2(hp[2]);
            float2 f3 = __half22float2(hp[3]);
            a0 += w * f0.x; a1 += w * f0.y;
            a2 += w * f1.x; a3 += w * f1.y;
            a4 += w * f2.x; a5 += w * f2.y;
            a6 += w * f3.x; a7 += w * f3.y;
        }
    }
    #pragma unroll
    for (int m = 8; m <= 32; m <<= 1) {
        a0 += __shfl_xor(a0, m, 64); a1 += __shfl_xor(a1, m, 64);
        a2 += __shfl_xor(a2, m, 64); a3 += __shfl_xor(a3, m, 64);
        a4 += __shfl_xor(a4, m, 64); a5 += __shfl_xor(a5, m, 64);
        a6 += __shfl_xor(a6, m, 64); a7 += __shfl_xor(a7, m, 64);
    }
    if (q == 0) {
        uint4 hq = *(const uint4*)(H + (size_t)v * 64 + fl * 8);
        const __half2* hp = (const __half2*)&hq;
        float2 s0 = __half22float2(hp[0]);
        float2 s1 = __half22float2(hp[1]);
        float2 s2 = __half22float2(hp[2]);
        float2 s3 = __half22float2(hp[3]);
        float4 b0 = *(const float4*)&bias[fl * 8];
        float4 b1 = *(const float4*)&bias[fl * 8 + 4];
        float r0 = dv * (a0 + dv * s0.x) + b0.x;
        float r1 = dv * (a1 + dv * s0.y) + b0.y;
        float r2 = dv * (a2 + dv * s1.x) + b0.z;
        float r3 = dv * (a3 + dv * s1.y) + b0.w;
        float r4 = dv * (a4 + dv * s2.x) + b1.x;
        float r5 = dv * (a5 + dv * s2.y) + b1.y;
        float r6 = dv * (a6 + dv * s3.x) + b1.z;
        float r7 = dv * (a7 + dv * s3.y) + b1.w;
        if (ELU) {
            r0 = r0 > 0.f ? r0 : expm1f(r0);
            r1 = r1 > 0.f ? r1 : expm1f(r1);
            r2 = r2 > 0.f ? r2 : expm1f(r2);
            r3 = r3 > 0.f ? r3 : expm1f(r3);
            r4 = r4 > 0.f ? r4 : expm1f(r4);
            r5 = r5 > 0.f ? r5 : expm1f(r5);
            r6 = r6 > 0.f ? r6 : expm1f(r6);
            r7 = r7 > 0.f ? r7 : expm1f(r7);
        }
        float4 o0; o0.x = r0; o0.y = r1; o0.z = r2; o0.w = r3;
        float4 o1; o1.x = r4; o1.y = r5; o1.z = r6; o1.w = r7;
        *(float4*)&out[(size_t)v * 64 + fl * 8] = o0;
        *(float4*)&out[(size_t)v * 64 + fl * 8 + 4] = o1;
    }
}

static inline size_t alignup(size_t x) { return (x + 255) & ~(size_t)255; }

extern "C" void kernel_launch(void* const* d_in, const int* in_sizes, int n_in,
                              void* d_out, int out_size, void* d_ws, size_t ws_size,
                              hipStream_t stream) {
    const float* x  = (const float*)d_in[0];
    const int*   ei = (const int*)d_in[1];
    const float* W1 = (const float*)d_in[2];
    const float* b1 = (const float*)d_in[3];
    const float* W2 = (const float*)d_in[4];
    const float* b2 = (const float*)d_in[5];
    const float* W3 = (const float*)d_in[6];
    const float* b3 = (const float*)d_in[7];
    float* out = (float*)d_out;

    const int N = in_sizes[0] / NFEAT_IN;  // 50000
    const int E = in_sizes[1] / 2;         // 800000
    const int* src = ei;
    const int* dst = ei + E;

    // workspace carve
    char* w = (char*)d_ws;
    int* cnt  = (int*)w;  w += alignup((size_t)N * sizeof(int));
    int* pos  = (int*)w;  w += alignup((size_t)N * sizeof(int));
    int* offs = (int*)w;  w += alignup((size_t)(N + 1) * sizeof(int));
    float* dinv = (float*)w; w += alignup((size_t)N * sizeof(float));
    int* bsum = (int*)w;  w += alignup((size_t)64 * sizeof(int));
    int2* esw = (int2*)w; w += alignup((size_t)E * sizeof(int2));
    __half* hH = (__half*)w; w += alignup((size_t)N * 128 * sizeof(__half));
    float* xA = (float*)w;   w += alignup((size_t)N * 128 * sizeof(float));

    const int nb = (N + SCAN_CHUNK - 1) / SCAN_CHUNK;  // 25 (<= 64 required)
    const int shard_sz = (N + NSHARD - 1) / NSHARD;    // 6250

    // --- build CSR + dinv (shared by all 3 layers) ---
    hipMemsetAsync(cnt, 0, (size_t)N * sizeof(int), stream);
    count_kernel<<<(E / 4 + 255) / 256, 256, 0, stream>>>(dst, cnt, E);
    reduce_kernel<<<nb, 256, 0, stream>>>(cnt, bsum, N);
    scanb_kernel<<<1, 64, 0, stream>>>(bsum, nb, offs, N);
    scan3_kernel<<<nb, 256, 0, stream>>>(cnt, bsum, offs, pos, dinv, N);
    fill_kernel<<<NSHARD * 128, 256, 0, stream>>>(src, dst, pos, dinv, esw, E, shard_sz);

    int gemm_grid = (N + 63) / 64;
    int agg_grid = (N + 3) / 4;

    // layer 1
    gemm_kernel<128><<<gemm_grid, 256, 0, stream>>>(x, W1, hH, N);
    agg128_kernel<true><<<agg_grid, 256, 0, stream>>>(hH, offs, esw, dinv, b1, xA, N);
    // layer 2
    gemm_kernel<128><<<gemm_grid, 256, 0, stream>>>(xA, W2, hH, N);
    agg128_kernel<true><<<agg_grid, 256, 0, stream>>>(hH, offs, esw, dinv, b2, xA, N);
    // layer 3 (128 -> 64), no ELU
    gemm_kernel<64><<<gemm_grid, 256, 0, stream>>>(xA, W3, hH, N);
    agg64_kernel<false><<<agg_grid, 256, 0, stream>>>(hH, offs, esw, dinv, b3, out, N);
}

// Round 6
// 237.596 us; speedup vs baseline: 2.2726x; 1.2202x over previous
//
#include <hip/hip_runtime.h>
#include <hip/hip_fp16.h>
#include <math.h>

// ---------------------------------------------------------------------------
// 3-layer GCN (PyG GCNConv semantics): per layer
//   h = x @ W ; out[v] = dinv[v]*(dinv[v]*h[v] + sum_e dinv[s]*h[s]) + b
// CSR + dinv built once. All hidden state fp16.
// GEMM = MFMA f16 16x16x32, swapped operands (A = W^T frags in LDS, B = X
// frags from global, D rows = h rows) -> h stored row-major fp16 directly.
// GEMM input X kept in "fragment-chunk" layout: chunk(m,k0) of 8 f16 at
//   byte ((m/16)*4 + k0/32)*1024 + (((k0/8)&3)*16 + (m&15))*16
// so a wave's B-frag load is base + lane*16 (fully coalesced dwordx4).
// Layer-1 X frags from a convert kernel; layer-2/3 from agg128's store.
// ---------------------------------------------------------------------------

#define NFEAT_IN 128
#define SCAN_CHUNK 2048
#define NSHARD 8

typedef _Float16 f16x8 __attribute__((ext_vector_type(8)));
typedef float f32x4 __attribute__((ext_vector_type(4)));

__global__ void zero_kernel(int4* __restrict__ p, int n4) {
    int i = blockIdx.x * blockDim.x + threadIdx.x;
    if (i < n4) { int4 z; z.x = z.y = z.z = z.w = 0; p[i] = z; }
}

__global__ void count_kernel(const int* __restrict__ dst, int* __restrict__ cnt, int E) {
    int i = blockIdx.x * blockDim.x + threadIdx.x;
    int base = i * 4;
    if (base + 4 <= E) {
        int4 d = *(const int4*)&dst[base];
        atomicAdd(&cnt[d.x], 1);
        atomicAdd(&cnt[d.y], 1);
        atomicAdd(&cnt[d.z], 1);
        atomicAdd(&cnt[d.w], 1);
    } else {
        for (int k = base; k < E; ++k) atomicAdd(&cnt[dst[k]], 1);
    }
}

__global__ __launch_bounds__(256) void reduce_kernel(const int* __restrict__ cnt,
                                                     int* __restrict__ bsum, int n) {
    __shared__ int wtot[4];
    int b = blockIdx.x, t = threadIdx.x;
    int base = b * SCAN_CHUNK + t * 8;
    int s = 0;
    if (base + 8 <= n) {
        int4 a = *(const int4*)&cnt[base];
        int4 c = *(const int4*)&cnt[base + 4];
        s = a.x + a.y + a.z + a.w + c.x + c.y + c.z + c.w;
    } else {
        for (int i = 0; i < 8; ++i) if (base + i < n) s += cnt[base + i];
    }
    int lane = t & 63, wid = t >> 6;
    #pragma unroll
    for (int off = 32; off > 0; off >>= 1) s += __shfl_down(s, off, 64);
    if (lane == 0) wtot[wid] = s;
    __syncthreads();
    if (t == 0) bsum[b] = wtot[0] + wtot[1] + wtot[2] + wtot[3];
}

__global__ void scanb_kernel(int* __restrict__ bsum, int nb, int* __restrict__ offs, int n) {
    int lane = threadIdx.x;
    int v = (lane < nb) ? bsum[lane] : 0;
    int inc = v;
    #pragma unroll
    for (int off = 1; off < 64; off <<= 1) {
        int t = __shfl_up(inc, off, 64);
        if (lane >= off) inc += t;
    }
    if (lane < nb) bsum[lane] = inc - v;  // exclusive
    if (lane == 63) offs[n] = inc;        // total
}

__global__ __launch_bounds__(256) void scan3_kernel(const int* __restrict__ cnt,
                                                    const int* __restrict__ bbase,
                                                    int* __restrict__ offs,
                                                    int* __restrict__ pos,
                                                    float* __restrict__ dinv, int n) {
    __shared__ int wtot[4];
    int b = blockIdx.x, t = threadIdx.x;
    int base = b * SCAN_CHUNK + t * 8;
    int v[8];
    #pragma unroll
    for (int i = 0; i < 8; ++i) v[i] = (base + i < n) ? cnt[base + i] : 0;
    int psum[8], s = 0;
    #pragma unroll
    for (int i = 0; i < 8; ++i) { psum[i] = s; s += v[i]; }
    int lane = t & 63, wid = t >> 6;
    int inc = s;
    #pragma unroll
    for (int off = 1; off < 64; off <<= 1) {
        int tt = __shfl_up(inc, off, 64);
        if (lane >= off) inc += tt;
    }
    if (lane == 63) wtot[wid] = inc;
    __syncthreads();
    int wb = 0;
    for (int w = 0; w < wid; ++w) wb += wtot[w];
    int tbase = bbase[b] + wb + (inc - s);
    #pragma unroll
    for (int i = 0; i < 8; ++i) {
        if (base + i < n) {
            int o = tbase + psum[i];
            offs[base + i] = o;
            pos[base + i] = o;
            dinv[base + i] = rsqrtf((float)(v[i] + 1));  // +1 self-loop
        }
    }
}

// dst-sharded fill (one XCD owns each esw slice -> no cross-XCD write amp)
__global__ __launch_bounds__(256) void fill_kernel(const int* __restrict__ src,
                                                   const int* __restrict__ dst,
                                                   int* __restrict__ pos,
                                                   const float* __restrict__ dinv,
                                                   int2* __restrict__ esw,
                                                   int E, int shard_sz) {
    int shard = blockIdx.x & (NSHARD - 1);
    int blk = blockIdx.x >> 3;
    int nblk = gridDim.x >> 3;
    int lo = shard * shard_sz;
    int hi = lo + shard_sz;
    int stride = nblk * blockDim.x;
    for (int i = blk * blockDim.x + threadIdx.x; i < E; i += stride) {
        int d = dst[i];
        if (d >= lo && d < hi) {
            int s = src[i];
            int p = atomicAdd(&pos[d], 1);
            int2 e;
            e.x = s;
            e.y = __float_as_int(dinv[s]);
            esw[p] = e;
        }
    }
}

// x fp32 row-major -> fragment-chunk fp16 layout (see header comment)
__global__ __launch_bounds__(256) void convx_kernel(const float* __restrict__ x,
                                                    f16x8* __restrict__ Xf, int nchunk) {
    int i = blockIdx.x * blockDim.x + threadIdx.x;
    if (i >= nchunk) return;
    int m = i >> 4, kc = i & 15;          // kc: which 8-feat chunk of the row
    float4 a = *(const float4*)&x[(size_t)m * 128 + kc * 8];
    float4 b = *(const float4*)&x[(size_t)m * 128 + kc * 8 + 4];
    f16x8 v;
    v[0] = (_Float16)a.x; v[1] = (_Float16)a.y; v[2] = (_Float16)a.z; v[3] = (_Float16)a.w;
    v[4] = (_Float16)b.x; v[5] = (_Float16)b.y; v[6] = (_Float16)b.z; v[7] = (_Float16)b.w;
    int kt = kc >> 2, sub = kc & 3;
    Xf[(size_t)((m >> 4) * 4 + kt) * 64 + sub * 16 + (m & 15)] = v;
}

// MFMA GEMM: Y[m, 0..BN) fp16 row-major = X(frag) @ W(fp32 [128][BN]).
// A = W^T fragment (LDS), B = X fragment (global, coalesced), 16x16x32_f16.
// Lane l holds h[mtile*16 + (l&15)][nt*16 + (l>>4)*4 + r] (m89 C/D layout).
template <int NT>  // BN = NT*16
__global__ __launch_bounds__(256) void mgemm_kernel(const f16x8* __restrict__ Xf,
                                                    const float* __restrict__ W,
                                                    __half* __restrict__ Y, int mtiles) {
    constexpr int BN = NT * 16;
    __shared__ f16x8 Wf[NT * 4 * 64];
    int t = threadIdx.x;
    // stage W as A-fragments: chunk c -> (nt, kt, lane); lane: n=nt*16+(l&15),
    // k0 = kt*32 + (l>>4)*8 ; 8 f16 along k (contiguous-k layout).
    #pragma unroll
    for (int i = 0; i < NT; ++i) {
        int c = t + i * 256;
        int nt = c >> 8;
        int kt = (c >> 6) & 3;
        int l = c & 63;
        int n = nt * 16 + (l & 15);
        int k0 = kt * 32 + (l >> 4) * 8;
        f16x8 v;
        #pragma unroll
        for (int j = 0; j < 8; ++j) v[j] = (_Float16)W[(size_t)(k0 + j) * BN + n];
        Wf[c] = v;
    }
    __syncthreads();
    int lane = t & 63;
    int mtile = blockIdx.x * 4 + (t >> 6);
    if (mtile >= mtiles) return;
    // B-fragments: coalesced 16B/lane
    const f16x8* xb = Xf + (size_t)mtile * 4 * 64;
    f16x8 bf[4];
    #pragma unroll
    for (int kt = 0; kt < 4; ++kt) bf[kt] = xb[kt * 64 + lane];
    f32x4 acc[NT];
    #pragma unroll
    for (int nt = 0; nt < NT; ++nt) acc[nt] = (f32x4){0.f, 0.f, 0.f, 0.f};
    #pragma unroll
    for (int kt = 0; kt < 4; ++kt) {
        #pragma unroll
        for (int nt = 0; nt < NT; ++nt) {
            f16x8 af = Wf[(nt * 4 + kt) * 64 + lane];
            acc[nt] = __builtin_amdgcn_mfma_f32_16x16x32_f16(af, bf[kt], acc[nt], 0, 0, 0);
        }
    }
    int m = mtile * 16 + (lane & 15);
    int nc0 = (lane >> 4) * 4;
    #pragma unroll
    for (int nt = 0; nt < NT; ++nt) {
        union { __half2 h2[2]; uint2 u; } pk;
        pk.h2[0] = __floats2half2_rn(acc[nt][0], acc[nt][1]);
        pk.h2[1] = __floats2half2_rn(acc[nt][2], acc[nt][3]);
        *(uint2*)&Y[(size_t)m * BN + nt * 16 + nc0] = pk.u;
    }
}

// CSR aggregation, 128 fp16 feats. Quarter-wave per edge (4 edges/gather
// instr, 16 in flight). Output: fp16 fragment-chunk layout for next GEMM.
__global__ __launch_bounds__(256) void agg128_kernel(const __half* __restrict__ H,
                                                     const int* __restrict__ offs,
                                                     const int2* __restrict__ esw,
                                                     const float* __restrict__ dinv,
                                                     const float* __restrict__ bias,
                                                     uint4* __restrict__ outf, int n) {
    int lane = threadIdx.x & 63;
    int q = lane >> 4;          // edge slot 0..3
    int fl = lane & 15;         // feature chunk: feats fl*8 .. fl*8+7
    int v = blockIdx.x * 4 + (threadIdx.x >> 6);
    if (v >= n) return;
    float dv = dinv[v];
    int e0 = offs[v], e1 = offs[v + 1];
    float a0=0.f,a1=0.f,a2=0.f,a3=0.f,a4=0.f,a5=0.f,a6=0.f,a7=0.f;
    int elast = e1 - 1;
    for (int base = e0 + q; base < e1; base += 16) {
        #pragma unroll
        for (int j = 0; j < 4; ++j) {
            int e = base + 4 * j;
            bool ok = (e < e1);
            int ec = ok ? e : elast;
            int2 p = esw[ec];
            float w = ok ? __int_as_float(p.y) : 0.f;
            uint4 hq = *(const uint4*)(H + (size_t)p.x * 128 + fl * 8);
            const __half2* hp = (const __half2*)&hq;
            float2 f0 = __half22float2(hp[0]);
            float2 f1 = __half22float2(hp[1]);
            float2 f2 = __half22float2(hp[2]);
            float2 f3 = __half22float2(hp[3]);
            a0 += w * f0.x; a1 += w * f0.y;
            a2 += w * f1.x; a3 += w * f1.y;
            a4 += w * f2.x; a5 += w * f2.y;
            a6 += w * f3.x; a7 += w * f3.y;
        }
    }
    #pragma unroll
    for (int m = 16; m <= 32; m <<= 1) {
        a0 += __shfl_xor(a0, m, 64); a1 += __shfl_xor(a1, m, 64);
        a2 += __shfl_xor(a2, m, 64); a3 += __shfl_xor(a3, m, 64);
        a4 += __shfl_xor(a4, m, 64); a5 += __shfl_xor(a5, m, 64);
        a6 += __shfl_xor(a6, m, 64); a7 += __shfl_xor(a7, m, 64);
    }
    if (q == 0) {
        uint4 hq = *(const uint4*)(H + (size_t)v * 128 + fl * 8);
        const __half2* hp = (const __half2*)&hq;
        float2 s0 = __half22float2(hp[0]);
        float2 s1 = __half22float2(hp[1]);
        float2 s2 = __half22float2(hp[2]);
        float2 s3 = __half22float2(hp[3]);
        float4 b0 = *(const float4*)&bias[fl * 8];
        float4 b1 = *(const float4*)&bias[fl * 8 + 4];
        float r0 = dv * (a0 + dv * s0.x) + b0.x;
        float r1 = dv * (a1 + dv * s0.y) + b0.y;
        float r2 = dv * (a2 + dv * s1.x) + b0.z;
        float r3 = dv * (a3 + dv * s1.y) + b0.w;
        float r4 = dv * (a4 + dv * s2.x) + b1.x;
        float r5 = dv * (a5 + dv * s2.y) + b1.y;
        float r6 = dv * (a6 + dv * s3.x) + b1.z;
        float r7 = dv * (a7 + dv * s3.y) + b1.w;
        r0 = r0 > 0.f ? r0 : expm1f(r0);
        r1 = r1 > 0.f ? r1 : expm1f(r1);
        r2 = r2 > 0.f ? r2 : expm1f(r2);
        r3 = r3 > 0.f ? r3 : expm1f(r3);
        r4 = r4 > 0.f ? r4 : expm1f(r4);
        r5 = r5 > 0.f ? r5 : expm1f(r5);
        r6 = r6 > 0.f ? r6 : expm1f(r6);
        r7 = r7 > 0.f ? r7 : expm1f(r7);
        union { __half2 h2[4]; uint4 u; } pk;
        pk.h2[0] = __floats2half2_rn(r0, r1);
        pk.h2[1] = __floats2half2_rn(r2, r3);
        pk.h2[2] = __floats2half2_rn(r4, r5);
        pk.h2[3] = __floats2half2_rn(r6, r7);
        // fragment-chunk address: (m=v, k0=fl*8)
        int blockc = (v >> 4) * 4 + (fl >> 2);
        int l2 = (fl & 3) * 16 + (v & 15);
        outf[(size_t)blockc * 64 + l2] = pk.u;
    }
}

// CSR aggregation, 64 fp16 feats -> fp32 row-major final output (no ELU).
__global__ __launch_bounds__(256) void agg64_kernel(const __half* __restrict__ H,
                                                    const int* __restrict__ offs,
                                                    const int2* __restrict__ esw,
                                                    const float* __restrict__ dinv,
                                                    const float* __restrict__ bias,
                                                    float* __restrict__ out, int n) {
    int lane = threadIdx.x & 63;
    int q = lane >> 3;          // edge slot 0..7
    int fl = lane & 7;          // feature chunk: feats fl*8 .. fl*8+7
    int v = blockIdx.x * 4 + (threadIdx.x >> 6);
    if (v >= n) return;
    float dv = dinv[v];
    int e0 = offs[v], e1 = offs[v + 1];
    float a0=0.f,a1=0.f,a2=0.f,a3=0.f,a4=0.f,a5=0.f,a6=0.f,a7=0.f;
    int elast = e1 - 1;
    for (int base = e0 + q; base < e1; base += 16) {
        #pragma unroll
        for (int j = 0; j < 2; ++j) {
            int e = base + 8 * j;
            bool ok = (e < e1);
            int ec = ok ? e : elast;
            int2 p = esw[ec];
            float w = ok ? __int_as_float(p.y) : 0.f;
            uint4 hq = *(const uint4*)(H + (size_t)p.x * 64 + fl * 8);
            const __half2* hp = (const __half2*)&hq;
            float2 f0 = __half22float2(hp[0]);
            float2 f1 = __half22float2(hp[1]);
            float2 f2 = __half22float2(hp[2]);
            float2 f3 = __half22float2(hp[3]);
            a0 += w * f0.x; a1 += w * f0.y;
            a2 += w * f1.x; a3 += w * f1.y;
            a4 += w * f2.x; a5 += w * f2.y;
            a6 += w * f3.x; a7 += w * f3.y;
        }
    }
    #pragma unroll
    for (int m = 8; m <= 32; m <<= 1) {
        a0 += __shfl_xor(a0, m, 64); a1 += __shfl_xor(a1, m, 64);
        a2 += __shfl_xor(a2, m, 64); a3 += __shfl_xor(a3, m, 64);
        a4 += __shfl_xor(a4, m, 64); a5 += __shfl_xor(a5, m, 64);
        a6 += __shfl_xor(a6, m, 64); a7 += __shfl_xor(a7, m, 64);
    }
    if (q == 0) {
        uint4 hq = *(const uint4*)(H + (size_t)v * 64 + fl * 8);
        const __half2* hp = (const __half2*)&hq;
        float2 s0 = __half22float2(hp[0]);
        float2 s1 = __half22float2(hp[1]);
        float2 s2 = __half22float2(hp[2]);
        float2 s3 = __half22float2(hp[3]);
        float4 b0 = *(const float4*)&bias[fl * 8];
        float4 b1 = *(const float4*)&bias[fl * 8 + 4];
        float4 o0, o1;
        o0.x = dv * (a0 + dv * s0.x) + b0.x;
        o0.y = dv * (a1 + dv * s0.y) + b0.y;
        o0.z = dv * (a2 + dv * s1.x) + b0.z;
        o0.w = dv * (a3 + dv * s1.y) + b0.w;
        o1.x = dv * (a4 + dv * s2.x) + b1.x;
        o1.y = dv * (a5 + dv * s2.y) + b1.y;
        o1.z = dv * (a6 + dv * s3.x) + b1.z;
        o1.w = dv * (a7 + dv * s3.y) + b1.w;
        *(float4*)&out[(size_t)v * 64 + fl * 8] = o0;
        *(float4*)&out[(size_t)v * 64 + fl * 8 + 4] = o1;
    }
}

static inline size_t alignup(size_t x) { return (x + 255) & ~(size_t)255; }

extern "C" void kernel_launch(void* const* d_in, const int* in_sizes, int n_in,
                              void* d_out, int out_size, void* d_ws, size_t ws_size,
                              hipStream_t stream) {
    const float* x  = (const float*)d_in[0];
    const int*   ei = (const int*)d_in[1];
    const float* W1 = (const float*)d_in[2];
    const float* b1 = (const float*)d_in[3];
    const float* W2 = (const float*)d_in[4];
    const float* b2 = (const float*)d_in[5];
    const float* W3 = (const float*)d_in[6];
    const float* b3 = (const float*)d_in[7];
    float* out = (float*)d_out;

    const int N = in_sizes[0] / NFEAT_IN;  // 50000 (divisible by 16)
    const int E = in_sizes[1] / 2;         // 800000
    const int* src = ei;
    const int* dst = ei + E;

    // workspace carve
    char* w = (char*)d_ws;
    int* cnt  = (int*)w;  w += alignup((size_t)N * sizeof(int));
    int* pos  = (int*)w;  w += alignup((size_t)N * sizeof(int));
    int* offs = (int*)w;  w += alignup((size_t)(N + 1) * sizeof(int));
    float* dinv = (float*)w; w += alignup((size_t)N * sizeof(float));
    int* bsum = (int*)w;  w += alignup((size_t)64 * sizeof(int));
    int2* esw = (int2*)w; w += alignup((size_t)E * sizeof(int2));
    __half* fA = (__half*)w; w += alignup((size_t)N * 128 * sizeof(__half));  // frag layout
    __half* hB = (__half*)w; w += alignup((size_t)N * 128 * sizeof(__half));  // row-major h

    const int nb = (N + SCAN_CHUNK - 1) / SCAN_CHUNK;  // 25 (<= 64 required)
    const int shard_sz = (N + NSHARD - 1) / NSHARD;    // 6250
    const int mtiles = N / 16;                          // 3125

    // --- build CSR + dinv (shared by all 3 layers) ---
    zero_kernel<<<(N / 4 + 255) / 256, 256, 0, stream>>>((int4*)cnt, N / 4);
    count_kernel<<<(E / 4 + 255) / 256, 256, 0, stream>>>(dst, cnt, E);
    reduce_kernel<<<nb, 256, 0, stream>>>(cnt, bsum, N);
    scanb_kernel<<<1, 64, 0, stream>>>(bsum, nb, offs, N);
    scan3_kernel<<<nb, 256, 0, stream>>>(cnt, bsum, offs, pos, dinv, N);
    fill_kernel<<<NSHARD * 128, 256, 0, stream>>>(src, dst, pos, dinv, esw, E, shard_sz);

    // layer-1 input -> fragment layout fp16
    convx_kernel<<<(N * 16 + 255) / 256, 256, 0, stream>>>(x, (f16x8*)fA, N * 16);

    int gemm_grid = (mtiles + 3) / 4;
    int agg_grid = (N + 3) / 4;

    // layer 1
    mgemm_kernel<8><<<gemm_grid, 256, 0, stream>>>((const f16x8*)fA, W1, hB, mtiles);
    agg128_kernel<<<agg_grid, 256, 0, stream>>>(hB, offs, esw, dinv, b1, (uint4*)fA, N);
    // layer 2
    mgemm_kernel<8><<<gemm_grid, 256, 0, stream>>>((const f16x8*)fA, W2, hB, mtiles);
    agg128_kernel<<<agg_grid, 256, 0, stream>>>(hB, offs, esw, dinv, b2, (uint4*)fA, N);
    // layer 3 (128 -> 64), no ELU
    mgemm_kernel<4><<<gemm_grid, 256, 0, stream>>>((const f16x8*)fA, W3, hB, mtiles);
    agg64_kernel<<<agg_grid, 256, 0, stream>>>(hB, offs, esw, dinv, b3, out, N);
}

// Round 7
// 236.084 us; speedup vs baseline: 2.2871x; 1.0064x over previous
//
#include <hip/hip_runtime.h>
#include <hip/hip_fp16.h>
#include <math.h>

// ---------------------------------------------------------------------------
// 3-layer GCN (PyG GCNConv semantics): per layer
//   h = x @ W ; out[v] = dinv[v]*(dinv[v]*h[v] + sum_e dinv[s]*h[s]) + b
// CSR + dinv built once. All hidden state fp16.
// GEMM = MFMA f16 16x16x32 swapped operands; X kept in fragment-chunk layout.
// Aggregation: wave/node, edge-slot lanes, v_fma_mix accumulate
// (fmaf((float)f16, w, acc) folds to v_fma_mix_f32), scalar-uniform full
// iterations + one masked tail (esw padded by 16 zero entries past E).
// ---------------------------------------------------------------------------

#define NFEAT_IN 128
#define SCAN_CHUNK 2048
#define NSHARD 8

typedef _Float16 f16x8 __attribute__((ext_vector_type(8)));
typedef float f32x4 __attribute__((ext_vector_type(4)));

__global__ void zero_kernel(int4* __restrict__ p, int n4) {
    int i = blockIdx.x * blockDim.x + threadIdx.x;
    if (i < n4) { int4 z; z.x = z.y = z.z = z.w = 0; p[i] = z; }
}

// dst-sharded count: all atomics for a cnt range issued from one XCD's blocks
__global__ __launch_bounds__(256) void count_kernel(const int* __restrict__ dst,
                                                    int* __restrict__ cnt,
                                                    int E, int shard_sz) {
    int shard = blockIdx.x & (NSHARD - 1);
    int blk = blockIdx.x >> 3;
    int nblk = gridDim.x >> 3;
    int lo = shard * shard_sz, hi = lo + shard_sz;
    int stride = nblk * blockDim.x;
    int E4 = E >> 2;
    for (int g = blk * blockDim.x + threadIdx.x; g < E4; g += stride) {
        int4 d = *(const int4*)&dst[g * 4];
        if (d.x >= lo && d.x < hi) atomicAdd(&cnt[d.x], 1);
        if (d.y >= lo && d.y < hi) atomicAdd(&cnt[d.y], 1);
        if (d.z >= lo && d.z < hi) atomicAdd(&cnt[d.z], 1);
        if (d.w >= lo && d.w < hi) atomicAdd(&cnt[d.w], 1);
    }
    if (blockIdx.x == 0 && threadIdx.x < (E & 3)) {
        int d = dst[(E & ~3) + threadIdx.x];
        atomicAdd(&cnt[d], 1);
    }
}

__global__ __launch_bounds__(256) void reduce_kernel(const int* __restrict__ cnt,
                                                     int* __restrict__ bsum, int n) {
    __shared__ int wtot[4];
    int b = blockIdx.x, t = threadIdx.x;
    int base = b * SCAN_CHUNK + t * 8;
    int s = 0;
    if (base + 8 <= n) {
        int4 a = *(const int4*)&cnt[base];
        int4 c = *(const int4*)&cnt[base + 4];
        s = a.x + a.y + a.z + a.w + c.x + c.y + c.z + c.w;
    } else {
        for (int i = 0; i < 8; ++i) if (base + i < n) s += cnt[base + i];
    }
    int lane = t & 63, wid = t >> 6;
    #pragma unroll
    for (int off = 32; off > 0; off >>= 1) s += __shfl_down(s, off, 64);
    if (lane == 0) wtot[wid] = s;
    __syncthreads();
    if (t == 0) bsum[b] = wtot[0] + wtot[1] + wtot[2] + wtot[3];
}

// single-wave scan of block sums; also zero the 16 esw padding entries
__global__ void scanb_kernel(int* __restrict__ bsum, int nb, int* __restrict__ offs,
                             int n, int2* __restrict__ esw, int E) {
    int lane = threadIdx.x;
    int v = (lane < nb) ? bsum[lane] : 0;
    int inc = v;
    #pragma unroll
    for (int off = 1; off < 64; off <<= 1) {
        int t = __shfl_up(inc, off, 64);
        if (lane >= off) inc += t;
    }
    if (lane < nb) bsum[lane] = inc - v;  // exclusive
    if (lane == 63) offs[n] = inc;        // total
    if (lane < 16) { int2 z; z.x = 0; z.y = 0; esw[E + lane] = z; }
}

__global__ __launch_bounds__(256) void scan3_kernel(const int* __restrict__ cnt,
                                                    const int* __restrict__ bbase,
                                                    int* __restrict__ offs,
                                                    int* __restrict__ pos,
                                                    float* __restrict__ dinv, int n) {
    __shared__ int wtot[4];
    int b = blockIdx.x, t = threadIdx.x;
    int base = b * SCAN_CHUNK + t * 8;
    int v[8];
    #pragma unroll
    for (int i = 0; i < 8; ++i) v[i] = (base + i < n) ? cnt[base + i] : 0;
    int psum[8], s = 0;
    #pragma unroll
    for (int i = 0; i < 8; ++i) { psum[i] = s; s += v[i]; }
    int lane = t & 63, wid = t >> 6;
    int inc = s;
    #pragma unroll
    for (int off = 1; off < 64; off <<= 1) {
        int tt = __shfl_up(inc, off, 64);
        if (lane >= off) inc += tt;
    }
    if (lane == 63) wtot[wid] = inc;
    __syncthreads();
    int wb = 0;
    for (int w = 0; w < wid; ++w) wb += wtot[w];
    int tbase = bbase[b] + wb + (inc - s);
    #pragma unroll
    for (int i = 0; i < 8; ++i) {
        if (base + i < n) {
            int o = tbase + psum[i];
            offs[base + i] = o;
            pos[base + i] = o;
            dinv[base + i] = rsqrtf((float)(v[i] + 1));  // +1 self-loop
        }
    }
}

// dst-sharded fill (one XCD owns each esw slice -> no cross-XCD write amp)
__global__ __launch_bounds__(256) void fill_kernel(const int* __restrict__ src,
                                                   const int* __restrict__ dst,
                                                   int* __restrict__ pos,
                                                   const float* __restrict__ dinv,
                                                   int2* __restrict__ esw,
                                                   int E, int shard_sz) {
    int shard = blockIdx.x & (NSHARD - 1);
    int blk = blockIdx.x >> 3;
    int nblk = gridDim.x >> 3;
    int lo = shard * shard_sz;
    int hi = lo + shard_sz;
    int stride = nblk * blockDim.x;
    for (int i = blk * blockDim.x + threadIdx.x; i < E; i += stride) {
        int d = dst[i];
        if (d >= lo && d < hi) {
            int s = src[i];
            int p = atomicAdd(&pos[d], 1);
            int2 e;
            e.x = s;
            e.y = __float_as_int(dinv[s]);
            esw[p] = e;
        }
    }
}

// x fp32 row-major -> fragment-chunk fp16 layout
__global__ __launch_bounds__(256) void convx_kernel(const float* __restrict__ x,
                                                    f16x8* __restrict__ Xf, int nchunk) {
    int i = blockIdx.x * blockDim.x + threadIdx.x;
    if (i >= nchunk) return;
    int m = i >> 4, kc = i & 15;
    float4 a = *(const float4*)&x[(size_t)m * 128 + kc * 8];
    float4 b = *(const float4*)&x[(size_t)m * 128 + kc * 8 + 4];
    f16x8 v;
    v[0] = (_Float16)a.x; v[1] = (_Float16)a.y; v[2] = (_Float16)a.z; v[3] = (_Float16)a.w;
    v[4] = (_Float16)b.x; v[5] = (_Float16)b.y; v[6] = (_Float16)b.z; v[7] = (_Float16)b.w;
    int kt = kc >> 2, sub = kc & 3;
    Xf[(size_t)((m >> 4) * 4 + kt) * 64 + sub * 16 + (m & 15)] = v;
}

// MFMA GEMM: Y[m, 0..BN) fp16 row-major = X(frag) @ W(fp32 [128][BN]).
template <int NT>  // BN = NT*16
__global__ __launch_bounds__(256) void mgemm_kernel(const f16x8* __restrict__ Xf,
                                                    const float* __restrict__ W,
                                                    __half* __restrict__ Y, int mtiles) {
    constexpr int BN = NT * 16;
    __shared__ f16x8 Wf[NT * 4 * 64];
    int t = threadIdx.x;
    #pragma unroll
    for (int i = 0; i < NT; ++i) {
        int c = t + i * 256;
        int nt = c >> 8;
        int kt = (c >> 6) & 3;
        int l = c & 63;
        int n = nt * 16 + (l & 15);
        int k0 = kt * 32 + (l >> 4) * 8;
        f16x8 v;
        #pragma unroll
        for (int j = 0; j < 8; ++j) v[j] = (_Float16)W[(size_t)(k0 + j) * BN + n];
        Wf[c] = v;
    }
    __syncthreads();
    int lane = t & 63;
    int mtile = blockIdx.x * 4 + (t >> 6);
    if (mtile >= mtiles) return;
    const f16x8* xb = Xf + (size_t)mtile * 4 * 64;
    f16x8 bf[4];
    #pragma unroll
    for (int kt = 0; kt < 4; ++kt) bf[kt] = xb[kt * 64 + lane];
    f32x4 acc[NT];
    #pragma unroll
    for (int nt = 0; nt < NT; ++nt) acc[nt] = (f32x4){0.f, 0.f, 0.f, 0.f};
    #pragma unroll
    for (int kt = 0; kt < 4; ++kt) {
        #pragma unroll
        for (int nt = 0; nt < NT; ++nt) {
            f16x8 af = Wf[(nt * 4 + kt) * 64 + lane];
            acc[nt] = __builtin_amdgcn_mfma_f32_16x16x32_f16(af, bf[kt], acc[nt], 0, 0, 0);
        }
    }
    int m = mtile * 16 + (lane & 15);
    int nc0 = (lane >> 4) * 4;
    #pragma unroll
    for (int nt = 0; nt < NT; ++nt) {
        union { __half2 h2[2]; uint2 u; } pk;
        pk.h2[0] = __floats2half2_rn(acc[nt][0], acc[nt][1]);
        pk.h2[1] = __floats2half2_rn(acc[nt][2], acc[nt][3]);
        *(uint2*)&Y[(size_t)m * BN + nt * 16 + nc0] = pk.u;
    }
}

// CSR aggregation, 128 fp16 feats. Quarter-wave edge slots; scalar-uniform
// full iterations (no masking) + one masked tail. v_fma_mix accumulate.
// Output: fp16 fragment-chunk layout for next GEMM (ELU applied).
__global__ __launch_bounds__(256) void agg128_kernel(const __half* __restrict__ H,
                                                     const int* __restrict__ offs,
                                                     const int2* __restrict__ esw,
                                                     const float* __restrict__ dinv,
                                                     const float* __restrict__ bias,
                                                     uint4* __restrict__ outf, int n) {
    int lane = threadIdx.x & 63;
    int q = lane >> 4;          // edge slot 0..3
    int fl = lane & 15;         // feature chunk: feats fl*8 .. fl*8+7
    int v = blockIdx.x * 4 + (threadIdx.x >> 6);
    if (v >= n) return;
    float dv = dinv[v];
    int e0 = offs[v], e1 = offs[v + 1];
    int cntE = e1 - e0;
    int nfull = cntE >> 4;
    const char* Hb = (const char*)H + fl * 16;
    float a[8];
    #pragma unroll
    for (int k = 0; k < 8; ++k) a[k] = 0.f;
    int e = e0 + q;
    for (int i = 0; i < nfull; ++i, e += 16) {
        #pragma unroll
        for (int j = 0; j < 4; ++j) {
            int2 p = esw[e + 4 * j];
            float w = __int_as_float(p.y);
            uint4 hq = *(const uint4*)(Hb + ((size_t)(unsigned)p.x << 8));
            const _Float16* hp = (const _Float16*)&hq;
            #pragma unroll
            for (int k = 0; k < 8; ++k) a[k] = fmaf((float)hp[k], w, a[k]);
        }
    }
    if (cntE & 15) {
        #pragma unroll
        for (int j = 0; j < 4; ++j) {
            int ee = e + 4 * j;
            int2 p = esw[ee];   // esw padded by 16 zero entries past E
            float w = (ee < e1) ? __int_as_float(p.y) : 0.f;
            uint4 hq = *(const uint4*)(Hb + ((size_t)(unsigned)p.x << 8));
            const _Float16* hp = (const _Float16*)&hq;
            #pragma unroll
            for (int k = 0; k < 8; ++k) a[k] = fmaf((float)hp[k], w, a[k]);
        }
    }
    #pragma unroll
    for (int m = 16; m <= 32; m <<= 1) {
        #pragma unroll
        for (int k = 0; k < 8; ++k) a[k] += __shfl_xor(a[k], m, 64);
    }
    if (q == 0) {
        uint4 hq = *(const uint4*)(Hb + ((size_t)(unsigned)v << 8));
        const _Float16* hp = (const _Float16*)&hq;
        float b[8];
        *(float4*)&b[0] = *(const float4*)&bias[fl * 8];
        *(float4*)&b[4] = *(const float4*)&bias[fl * 8 + 4];
        float r[8];
        #pragma unroll
        for (int k = 0; k < 8; ++k) {
            float t = fmaf((float)hp[k], dv, a[k]);
            r[k] = fmaf(dv, t, b[k]);
            r[k] = r[k] > 0.f ? r[k] : expm1f(r[k]);
        }
        union { __half2 h2[4]; uint4 u; } pk;
        pk.h2[0] = __floats2half2_rn(r[0], r[1]);
        pk.h2[1] = __floats2half2_rn(r[2], r[3]);
        pk.h2[2] = __floats2half2_rn(r[4], r[5]);
        pk.h2[3] = __floats2half2_rn(r[6], r[7]);
        int blockc = (v >> 4) * 4 + (fl >> 2);
        int l2 = (fl & 3) * 16 + (v & 15);
        outf[(size_t)blockc * 64 + l2] = pk.u;
    }
}

// CSR aggregation, 64 fp16 feats -> fp32 row-major final output (no ELU).
__global__ __launch_bounds__(256) void agg64_kernel(const __half* __restrict__ H,
                                                    const int* __restrict__ offs,
                                                    const int2* __restrict__ esw,
                                                    const float* __restrict__ dinv,
                                                    const float* __restrict__ bias,
                                                    float* __restrict__ out, int n) {
    int lane = threadIdx.x & 63;
    int q = lane >> 3;          // edge slot 0..7
    int fl = lane & 7;          // feature chunk: feats fl*8 .. fl*8+7
    int v = blockIdx.x * 4 + (threadIdx.x >> 6);
    if (v >= n) return;
    float dv = dinv[v];
    int e0 = offs[v], e1 = offs[v + 1];
    int cntE = e1 - e0;
    int nfull = cntE >> 4;
    const char* Hb = (const char*)H + fl * 16;
    float a[8];
    #pragma unroll
    for (int k = 0; k < 8; ++k) a[k] = 0.f;
    int e = e0 + q;
    for (int i = 0; i < nfull; ++i, e += 16) {
        #pragma unroll
        for (int j = 0; j < 2; ++j) {
            int2 p = esw[e + 8 * j];
            float w = __int_as_float(p.y);
            uint4 hq = *(const uint4*)(Hb + ((size_t)(unsigned)p.x << 7));
            const _Float16* hp = (const _Float16*)&hq;
            #pragma unroll
            for (int k = 0; k < 8; ++k) a[k] = fmaf((float)hp[k], w, a[k]);
        }
    }
    if (cntE & 15) {
        #pragma unroll
        for (int j = 0; j < 2; ++j) {
            int ee = e + 8 * j;
            int2 p = esw[ee];   // padded past E
            float w = (ee < e1) ? __int_as_float(p.y) : 0.f;
            uint4 hq = *(const uint4*)(Hb + ((size_t)(unsigned)p.x << 7));
            const _Float16* hp = (const _Float16*)&hq;
            #pragma unroll
            for (int k = 0; k < 8; ++k) a[k] = fmaf((float)hp[k], w, a[k]);
        }
    }
    #pragma unroll
    for (int m = 8; m <= 32; m <<= 1) {
        #pragma unroll
        for (int k = 0; k < 8; ++k) a[k] += __shfl_xor(a[k], m, 64);
    }
    if (q == 0) {
        uint4 hq = *(const uint4*)(Hb + ((size_t)(unsigned)v << 7));
        const _Float16* hp = (const _Float16*)&hq;
        float b[8];
        *(float4*)&b[0] = *(const float4*)&bias[fl * 8];
        *(float4*)&b[4] = *(const float4*)&bias[fl * 8 + 4];
        float r[8];
        #pragma unroll
        for (int k = 0; k < 8; ++k) {
            float t = fmaf((float)hp[k], dv, a[k]);
            r[k] = fmaf(dv, t, b[k]);
        }
        float4 o0, o1;
        o0.x = r[0]; o0.y = r[1]; o0.z = r[2]; o0.w = r[3];
        o1.x = r[4]; o1.y = r[5]; o1.z = r[6]; o1.w = r[7];
        *(float4*)&out[(size_t)v * 64 + fl * 8] = o0;
        *(float4*)&out[(size_t)v * 64 + fl * 8 + 4] = o1;
    }
}

static inline size_t alignup(size_t x) { return (x + 255) & ~(size_t)255; }

extern "C" void kernel_launch(void* const* d_in, const int* in_sizes, int n_in,
                              void* d_out, int out_size, void* d_ws, size_t ws_size,
                              hipStream_t stream) {
    const float* x  = (const float*)d_in[0];
    const int*   ei = (const int*)d_in[1];
    const float* W1 = (const float*)d_in[2];
    const float* b1 = (const float*)d_in[3];
    const float* W2 = (const float*)d_in[4];
    const float* b2 = (const float*)d_in[5];
    const float* W3 = (const float*)d_in[6];
    const float* b3 = (const float*)d_in[7];
    float* out = (float*)d_out;

    const int N = in_sizes[0] / NFEAT_IN;  // 50000 (divisible by 16)
    const int E = in_sizes[1] / 2;         // 800000
    const int* src = ei;
    const int* dst = ei + E;

    // workspace carve
    char* w = (char*)d_ws;
    int* cnt  = (int*)w;  w += alignup((size_t)N * sizeof(int));
    int* pos  = (int*)w;  w += alignup((size_t)N * sizeof(int));
    int* offs = (int*)w;  w += alignup((size_t)(N + 1) * sizeof(int));
    float* dinv = (float*)w; w += alignup((size_t)N * sizeof(float));
    int* bsum = (int*)w;  w += alignup((size_t)64 * sizeof(int));
    int2* esw = (int2*)w; w += alignup((size_t)(E + 16) * sizeof(int2));
    __half* fA = (__half*)w; w += alignup((size_t)N * 128 * sizeof(__half));  // frag layout
    __half* hB = (__half*)w; w += alignup((size_t)N * 128 * sizeof(__half));  // row-major h

    const int nb = (N + SCAN_CHUNK - 1) / SCAN_CHUNK;  // 25 (<= 64 required)
    const int shard_sz = (N + NSHARD - 1) / NSHARD;    // 6250
    const int mtiles = N / 16;                          // 3125

    // --- build CSR + dinv (shared by all 3 layers) ---
    zero_kernel<<<(N / 4 + 255) / 256, 256, 0, stream>>>((int4*)cnt, N / 4);
    count_kernel<<<NSHARD * 128, 256, 0, stream>>>(dst, cnt, E, shard_sz);
    reduce_kernel<<<nb, 256, 0, stream>>>(cnt, bsum, N);
    scanb_kernel<<<1, 64, 0, stream>>>(bsum, nb, offs, N, esw, E);
    scan3_kernel<<<nb, 256, 0, stream>>>(cnt, bsum, offs, pos, dinv, N);
    fill_kernel<<<NSHARD * 128, 256, 0, stream>>>(src, dst, pos, dinv, esw, E, shard_sz);

    // layer-1 input -> fragment layout fp16
    convx_kernel<<<(N * 16 + 255) / 256, 256, 0, stream>>>(x, (f16x8*)fA, N * 16);

    int gemm_grid = (mtiles + 3) / 4;
    int agg_grid = (N + 3) / 4;

    // layer 1
    mgemm_kernel<8><<<gemm_grid, 256, 0, stream>>>((const f16x8*)fA, W1, hB, mtiles);
    agg128_kernel<<<agg_grid, 256, 0, stream>>>(hB, offs, esw, dinv, b1, (uint4*)fA, N);
    // layer 2
    mgemm_kernel<8><<<gemm_grid, 256, 0, stream>>>((const f16x8*)fA, W2, hB, mtiles);
    agg128_kernel<<<agg_grid, 256, 0, stream>>>(hB, offs, esw, dinv, b2, (uint4*)fA, N);
    // layer 3 (128 -> 64), no ELU
    mgemm_kernel<4><<<gemm_grid, 256, 0, stream>>>((const f16x8*)fA, W3, hB, mtiles);
    agg64_kernel<<<agg_grid, 256, 0, stream>>>(hB, offs, esw, dinv, b3, out, N);
}